// Round 2
// baseline (53355.768 us; speedup 1.0000x reference)
//
#include <hip/hip_runtime.h>
#include <hip/hip_bf16.h>
#include <math.h>

#define PAD_ID 0
#define UNK_ID 1
#define START_ID 2
#define END_ID 3

constexpr int B = 16, S = 512, T = 128, V = 32000, E = 128, H = 256, D = 512;
constexpr int C3 = 1536;        // 3*D
constexpr int VO = 31997;       // V-3
constexpr int JS = 32000;       // padded col stride for outT

__device__ __forceinline__ float sigm(float x) { return 1.0f / (1.0f + __expf(-x)); }

// ---------------- weight packing: W[4H][K] -> P[k][u] = float4{W[u][k],W[H+u][k],W[2H+u][k],W[3H+u][k]}
__global__ void pack4_kernel(const float* __restrict__ W, float4* __restrict__ P, int Hn, int K) {
    int i = blockIdx.x * blockDim.x + threadIdx.x;
    if (i >= K * Hn) return;
    int k = i / Hn, u = i - k * Hn;
    float4 v;
    v.x = W[(size_t)(0 * Hn + u) * K + k];
    v.y = W[(size_t)(1 * Hn + u) * K + k];
    v.z = W[(size_t)(2 * Hn + u) * K + k];
    v.w = W[(size_t)(3 * Hn + u) * K + k];
    P[(size_t)k * Hn + u] = v;
}

// ---------------- encoder layer-0 gate preactivations for both directions
// grid: S*B blocks (n = s*B+b), 256 threads
__global__ void enc0_gates(const int* __restrict__ ids, const float* __restrict__ emb,
                           const float4* __restrict__ Pf, const float* __restrict__ bf_,
                           const float4* __restrict__ Pb, const float* __restrict__ bb_,
                           float* __restrict__ Gf, float* __restrict__ Gb) {
    int n = blockIdx.x;
    int s = n / B, b = n - s * B;
    int u = threadIdx.x;
    __shared__ float xr[E];
    int tok = ids[b * S + s];
    if (tok >= V) tok = UNK_ID;
    if (u < E) xr[u] = emb[(size_t)tok * E + u];
    __syncthreads();
    float a0 = bf_[0 * H + u], a1 = bf_[1 * H + u], a2 = bf_[2 * H + u], a3 = bf_[3 * H + u];
#pragma unroll 4
    for (int k = 0; k < E; k++) {
        float xv = xr[k]; float4 w = Pf[k * H + u];
        a0 += xv * w.x; a1 += xv * w.y; a2 += xv * w.z; a3 += xv * w.w;
    }
    float* g = Gf + (size_t)n * 4 * H;
    g[0 * H + u] = a0; g[1 * H + u] = a1; g[2 * H + u] = a2; g[3 * H + u] = a3;
    a0 = bb_[0 * H + u]; a1 = bb_[1 * H + u]; a2 = bb_[2 * H + u]; a3 = bb_[3 * H + u];
#pragma unroll 4
    for (int k = 0; k < E; k++) {
        float xv = xr[k]; float4 w = Pb[k * H + u];
        a0 += xv * w.x; a1 += xv * w.y; a2 += xv * w.z; a3 += xv * w.w;
    }
    g = Gb + (size_t)n * 4 * H;
    g[0 * H + u] = a0; g[1 * H + u] = a1; g[2 * H + u] = a2; g[3 * H + u] = a3;
}

// ---------------- encoder layer-1 gate preactivations (input = concat(h0f,h0b))
__global__ void enc1_gates(const float* __restrict__ h0f, const float* __restrict__ h0b,
                           const float4* __restrict__ Pf, const float* __restrict__ bf_,
                           const float4* __restrict__ Pb, const float* __restrict__ bb_,
                           float* __restrict__ Gf, float* __restrict__ Gb) {
    int n = blockIdx.x;      // s*B+b
    int u = threadIdx.x;     // 256
    __shared__ float xr[D];
    xr[u] = h0f[(size_t)n * H + u];
    xr[H + u] = h0b[(size_t)n * H + u];
    __syncthreads();
    float a0 = bf_[0 * H + u], a1 = bf_[1 * H + u], a2 = bf_[2 * H + u], a3 = bf_[3 * H + u];
#pragma unroll 4
    for (int k = 0; k < D; k++) {
        float xv = xr[k]; float4 w = Pf[k * H + u];
        a0 += xv * w.x; a1 += xv * w.y; a2 += xv * w.z; a3 += xv * w.w;
    }
    float* g = Gf + (size_t)n * 4 * H;
    g[0 * H + u] = a0; g[1 * H + u] = a1; g[2 * H + u] = a2; g[3 * H + u] = a3;
    a0 = bb_[0 * H + u]; a1 = bb_[1 * H + u]; a2 = bb_[2 * H + u]; a3 = bb_[3 * H + u];
#pragma unroll 4
    for (int k = 0; k < D; k++) {
        float xv = xr[k]; float4 w = Pb[k * H + u];
        a0 += xv * w.x; a1 += xv * w.y; a2 += xv * w.z; a3 += xv * w.w;
    }
    g = Gb + (size_t)n * 4 * H;
    g[0 * H + u] = a0; g[1 * H + u] = a1; g[2 * H + u] = a2; g[3 * H + u] = a3;
}

// ---------------- bidirectional encoder scan for one layer. grid 32 = b*2+dir, 256 threads.
__global__ void enc_scan(const float* __restrict__ Gf, const float* __restrict__ Gb,
                         const float4* __restrict__ Pf, const float4* __restrict__ Pb,
                         float* __restrict__ hof, float* __restrict__ hob,
                         float* __restrict__ hfin /* [B][2H] */) {
    int blk = blockIdx.x;
    int dirb = blk & 1, b = blk >> 1;   // same-dir blocks land on same XCD (bid%8 parity)
    int u = threadIdx.x;
    const float* G = dirb ? Gb : Gf;
    const float4* P = dirb ? Pb : Pf;
    float* ho = dirb ? hob : hof;
    __shared__ float hs[H];
    float c = 0.f, h = 0.f;
    hs[u] = 0.f;
    __syncthreads();
    for (int step = 0; step < S; step++) {
        int s = dirb ? (S - 1 - step) : step;
        const float* g = G + ((size_t)(s * B + b)) * (4 * H);
        float a0 = g[u], a1 = g[H + u], a2 = g[2 * H + u], a3 = g[3 * H + u];
#pragma unroll 4
        for (int k = 0; k < H; k++) {
            float hk = hs[k]; float4 w = P[k * H + u];
            a0 += hk * w.x; a1 += hk * w.y; a2 += hk * w.z; a3 += hk * w.w;
        }
        float ig = sigm(a0), fg = sigm(a1), gg = tanhf(a2), og = sigm(a3);
        c = fg * c + ig * gg;
        h = og * tanhf(c);
        __syncthreads();
        hs[u] = h;
        ho[((size_t)(s * B + b)) * H + u] = h;
        __syncthreads();
    }
    hfin[b * (2 * H) + dirb * H + u] = h;
}

// ---------------- decoder layer-0 input gates (teacher tokens). grid T*B (n=t*B+b), 512 thr.
__global__ void dec0_gates(const int* __restrict__ tgt, const float* __restrict__ emb,
                           const float4* __restrict__ P, const float* __restrict__ bias,
                           float* __restrict__ G) {
    int n = blockIdx.x;
    int t = n / B, b = n - t * B;
    int u = threadIdx.x;
    __shared__ float xr[E];
    int tok;
    if (t == 0) tok = START_ID;
    else { tok = tgt[b * T + (t - 1)]; if (tok >= V) tok = UNK_ID; }
    if (u < E) xr[u] = emb[(size_t)tok * E + u];
    __syncthreads();
    float a0 = bias[0 * D + u], a1 = bias[1 * D + u], a2 = bias[2 * D + u], a3 = bias[3 * D + u];
#pragma unroll 4
    for (int k = 0; k < E; k++) {
        float xv = xr[k]; float4 w = P[k * D + u];
        a0 += xv * w.x; a1 += xv * w.y; a2 += xv * w.z; a3 += xv * w.w;
    }
    float* g = G + (size_t)n * 4 * D;
    g[0 * D + u] = a0; g[1 * D + u] = a1; g[2 * D + u] = a2; g[3 * D + u] = a3;
}

// ---------------- decoder 2-layer scan. grid B=16 blocks, 512 threads (u = hidden unit).
__global__ void __launch_bounds__(512) dec_scan(
        const float* __restrict__ G0, const float4* __restrict__ P0,
        const float4* __restrict__ P1i, const float4* __restrict__ P1h,
        const float* __restrict__ b1, const float* __restrict__ hinit,
        float* __restrict__ h1out) {
    int b = blockIdx.x;
    int u = threadIdx.x;
    __shared__ float hs0[D], hs1[D];
    float c0 = 0.f, c1 = 0.f;
    hs0[u] = hinit[b * D + u];
    hs1[u] = hinit[B * D + b * D + u];
    float bi0 = b1[u], bi1 = b1[D + u], bi2 = b1[2 * D + u], bi3 = b1[3 * D + u];
    __syncthreads();
    for (int t = 0; t < T; t++) {
        const float* g = G0 + ((size_t)(t * B + b)) * (4 * D);
        float a0 = g[u], a1 = g[D + u], a2 = g[2 * D + u], a3 = g[3 * D + u];
#pragma unroll 4
        for (int k = 0; k < D; k++) {
            float hk = hs0[k]; float4 w = P0[k * D + u];
            a0 += hk * w.x; a1 += hk * w.y; a2 += hk * w.z; a3 += hk * w.w;
        }
        float ig = sigm(a0), fg = sigm(a1), gg = tanhf(a2), og = sigm(a3);
        c0 = fg * c0 + ig * gg;
        float h0n = og * tanhf(c0);
        __syncthreads();          // all reads of hs0 done
        hs0[u] = h0n;
        __syncthreads();          // new hs0 visible
        a0 = bi0; a1 = bi1; a2 = bi2; a3 = bi3;
#pragma unroll 4
        for (int k = 0; k < D; k++) {
            float hk = hs0[k]; float4 w = P1i[k * D + u];
            a0 += hk * w.x; a1 += hk * w.y; a2 += hk * w.z; a3 += hk * w.w;
        }
#pragma unroll 4
        for (int k = 0; k < D; k++) {
            float hk = hs1[k]; float4 w = P1h[k * D + u];
            a0 += hk * w.x; a1 += hk * w.y; a2 += hk * w.z; a3 += hk * w.w;
        }
        ig = sigm(a0); fg = sigm(a1); gg = tanhf(a2); og = sigm(a3);
        c1 = fg * c1 + ig * gg;
        float h1n = og * tanhf(c1);
        __syncthreads();          // all reads of hs1 done
        hs1[u] = h1n;
        h1out[((size_t)(t * B + b)) * D + u] = h1n;
        __syncthreads();
    }
}

// ---------------- transpose enc hidden to [b][k(512)][s] for coalesced score dots
__global__ void build_encht(const float* __restrict__ h1f, const float* __restrict__ h1b,
                            float* __restrict__ et) {
    int blk = blockIdx.x;                 // b*256 + kt*16 + st
    int b = blk >> 8, rem = blk & 255;
    int kt = rem >> 4, st = rem & 15;
    int c = threadIdx.x & 31, r = threadIdx.x >> 5;   // r in 0..7
    __shared__ float tile[32][33];
#pragma unroll
    for (int i = 0; i < 4; i++) {
        int sl = r + i * 8;               // s_local
        int s = st * 32 + sl;
        int k = kt * 32 + c;              // lane-contiguous over k
        float v = (k < H) ? h1f[((size_t)(s * B + b)) * H + k]
                          : h1b[((size_t)(s * B + b)) * H + (k - H)];
        tile[c][sl] = v;                  // tile[k_local][s_local]
    }
    __syncthreads();
#pragma unroll
    for (int i = 0; i < 4; i++) {
        int kl = r + i * 8;
        et[(size_t)b * D * S + (size_t)(kt * 32 + kl) * S + st * 32 + c] = tile[kl][c];
    }
}

// ---------------- q projections. grid T*B (n=t*B+b), 512 threads
__global__ void qproj(const float* __restrict__ h1d, const float* __restrict__ Wenc,
                      const float* __restrict__ Wdec, float* __restrict__ qe, float* __restrict__ qd) {
    int n = blockIdx.x;
    int o = threadIdx.x;
    __shared__ float hr[D];
    hr[o] = h1d[(size_t)n * D + o];
    __syncthreads();
    float ae = 0.f, ad = 0.f;
#pragma unroll 4
    for (int k = 0; k < D; k++) {
        float hk = hr[k];
        ae += hk * Wenc[k * D + o];
        ad += hk * Wdec[k * D + o];
    }
    qe[(size_t)n * D + o] = ae;
    qd[(size_t)n * D + o] = ad;
}

// ---------------- e = exp(min(score,30)). grid B*T (bt=b*T+t), 512 threads (s)
__global__ void escore(const float* __restrict__ qe, const float* __restrict__ et,
                       float* __restrict__ ew) {
    int bt = blockIdx.x;
    int b = bt / T, t = bt - b * T;
    int sx = threadIdx.x;
    __shared__ float q[D];
    q[sx] = qe[((size_t)(t * B + b)) * D + sx];
    __syncthreads();
    float acc = 0.f;
    const float* eb = et + (size_t)b * D * S + sx;
#pragma unroll 4
    for (int k = 0; k < D; k++) { acc += q[k] * eb[0]; eb += S; }
    acc = fminf(acc, 30.0f);
    ew[(size_t)bt * S + sx] = __expf(acc);
}

// ---------------- temporal normalization (prefix over t, in place)
__global__ void temporal_k(float* __restrict__ ew) {
    int i = blockIdx.x * blockDim.x + threadIdx.x;
    if (i >= B * S) return;
    int b = i / S, sx = i - b * S;
    float cum = 0.f;
    for (int t = 0; t < T; t++) {
        size_t idx = ((size_t)(b * T + t)) * S + sx;
        float v = ew[idx];
        ew[idx] = v / (t == 0 ? 1.0f : (cum + 1e-8f));
        cum += v;
    }
}

// ---------------- attention softmax over s + enc context + copy prob. grid B*T, 512 thr
__global__ void attnctx(const float* __restrict__ ew, const int* __restrict__ ids,
                        const int* __restrict__ tgt,
                        const float* __restrict__ h1f, const float* __restrict__ h1b,
                        float* __restrict__ ectx, float* __restrict__ copyp) {
    int bt = blockIdx.x;
    int b = bt / T, t = bt - b * T;
    int tid = threadIdx.x;
    __shared__ float aw[S];
    __shared__ float red[512];
    float v = ew[(size_t)bt * S + tid];
    int tok = ids[b * S + tid];
    bool pad = (tok == PAD_ID);
    float vm = pad ? -INFINITY : v;
    red[tid] = vm; __syncthreads();
    for (int w = 256; w > 0; w >>= 1) { if (tid < w) red[tid] = fmaxf(red[tid], red[tid + w]); __syncthreads(); }
    float m = red[0]; __syncthreads();
    float ex = pad ? 0.f : __expf(vm - m);
    red[tid] = ex; __syncthreads();
    for (int w = 256; w > 0; w >>= 1) { if (tid < w) red[tid] += red[tid + w]; __syncthreads(); }
    float Z = red[0]; __syncthreads();
    float a = ex / Z;
    aw[tid] = a;
    int nt = tgt[b * T + t];
    red[tid] = (tok == nt) ? a : 0.f; __syncthreads();
    for (int w = 256; w > 0; w >>= 1) { if (tid < w) red[tid] += red[tid + w]; __syncthreads(); }
    if (tid == 0) copyp[bt] = red[0];
    __syncthreads();
    int d = tid;
    const float* hp = (d < H) ? (h1f + (size_t)b * H + d) : (h1b + (size_t)b * H + (d - H));
    float acc = 0.f;
#pragma unroll 4
    for (int s2 = 0; s2 < S; s2++) { acc += aw[s2] * hp[0]; hp += B * H; }
    ectx[(size_t)bt * D + d] = acc;
}

// ---------------- intra-decoder attention. grid B*T, 128 threads
__global__ void decattn(const float* __restrict__ qd, const float* __restrict__ h1d,
                        float* __restrict__ dctx) {
    int bt = blockIdx.x;
    int b = bt / T, t = bt - b * T;
    int tid = threadIdx.x;
    __shared__ float q[D];
    __shared__ float wl[T];
    __shared__ float red[128];
    for (int i = tid; i < D; i += 128) q[i] = qd[((size_t)(t * B + b)) * D + i];
    __syncthreads();
    float sc = -INFINITY;
    if (tid < t) {
        const float* hu = h1d + ((size_t)(tid * B + b)) * D;
        float a = 0.f;
#pragma unroll 4
        for (int k = 0; k < D; k++) a += q[k] * hu[k];
        sc = a;
    }
    red[tid] = sc; __syncthreads();
    for (int w = 64; w > 0; w >>= 1) { if (tid < w) red[tid] = fmaxf(red[tid], red[tid + w]); __syncthreads(); }
    float m = red[0]; __syncthreads();
    float ex = (tid < t) ? __expf(sc - m) : 0.f;
    red[tid] = ex; __syncthreads();
    for (int w = 64; w > 0; w >>= 1) { if (tid < w) red[tid] += red[tid + w]; __syncthreads(); }
    float Z = red[0]; __syncthreads();
    wl[tid] = (t > 0) ? (ex / Z) : 0.f;
    __syncthreads();
    for (int d = tid; d < D; d += 128) {
        float acc = 0.f;
        for (int u = 0; u < t; u++) acc += wl[u] * h1d[((size_t)(u * B + b)) * D + d];
        dctx[(size_t)bt * D + d] = acc;
    }
}

// ---------------- concat + p_gen. grid B*T, 512 threads
__global__ void concat_k(const float* __restrict__ h1d, const float* __restrict__ ectx,
                         const float* __restrict__ dctx, const float* __restrict__ sW,
                         const float* __restrict__ sb, float* __restrict__ cc,
                         float* __restrict__ pgen) {
    int bt = blockIdx.x;
    int b = bt / T, t = bt - b * T;
    int d = threadIdx.x;
    __shared__ float red[512];
    float v0 = h1d[((size_t)(t * B + b)) * D + d];
    float v1 = ectx[(size_t)bt * D + d];
    float v2 = dctx[(size_t)bt * D + d];
    float* c = cc + (size_t)bt * C3;
    c[d] = v0; c[D + d] = v1; c[2 * D + d] = v2;
    red[d] = v0 * sW[d] + v1 * sW[D + d] + v2 * sW[2 * D + d];
    __syncthreads();
    for (int w = 256; w > 0; w >>= 1) { if (d < w) red[d] += red[d + w]; __syncthreads(); }
    if (d == 0) pgen[bt] = 1.f / (1.f + __expf(-(red[0] + sb[0])));
}

// ---------------- out_projT[k][j] = tanh(emb[3+j] . Wvoc[:,k]) stored bf16, k-major.
// grid 1000 blocks (32 j each), 256 threads = (jl = tid&31, kq = tid>>5)
__global__ void outprojT_k(const float* __restrict__ emb, const float* __restrict__ Wvoc,
                           __hip_bfloat16* __restrict__ outT) {
    int j0 = blockIdx.x * 32;
    int jl = threadIdx.x & 31, kq = threadIdx.x >> 5;   // kq in 0..7
    __shared__ float er[32][E + 1];                      // +1 pad: bank-conflict-free
    for (int i = threadIdx.x; i < 32 * E; i += 256) {
        int jj = i >> 7, e = i & 127;
        int j = j0 + jj;
        er[jj][e] = (j < VO) ? emb[(size_t)(3 + j) * E + e] : 0.f;
    }
    __syncthreads();
    int j = j0 + jl;
#pragma unroll 2
    for (int i = 0; i < C3 / 8; i++) {
        int k = i * 8 + kq;                              // all 32 lanes share k -> broadcast Wvoc loads
        float acc = 0.f;
#pragma unroll 4
        for (int e = 0; e < E; e++) acc += er[jl][e] * Wvoc[(size_t)e * C3 + k];
        if (j < VO) outT[(size_t)k * JS + j] = __float2bfloat16(tanhf(acc));
    }
}

// ---------------- fused vocab GEMM + online softmax + final prob. grid 256 blocks (8 rows), 512 thr
__global__ void __launch_bounds__(512) vocab_k(
        const __hip_bfloat16* __restrict__ outT, const float* __restrict__ cc,
        const float* __restrict__ ob, const int* __restrict__ tgt,
        const float* __restrict__ pgen, const float* __restrict__ copyp,
        float* __restrict__ pout) {
    int row0 = blockIdx.x * 8;
    int tid = threadIdx.x;
    __shared__ float c_s[8 * C3];
    __shared__ float redm[512], reds[512];
    __shared__ float Mrow[8], Srow[8], glds[8];
    for (int i = tid; i < 8 * C3; i += 512) c_s[i] = cc[(size_t)row0 * C3 + i];
    int jstar[8];
#pragma unroll
    for (int r = 0; r < 8; r++) {
        int row = row0 + r, b = row >> 7, t = row & 127;
        int nt = tgt[b * T + t];
        int ix = nt - 3;
        ix = ix < 0 ? 0 : (ix > VO - 1 ? VO - 1 : ix);
        jstar[r] = ix;
    }
    __syncthreads();
    float m[8], ssum[8], gl[8];
#pragma unroll
    for (int r = 0; r < 8; r++) { m[r] = -INFINITY; ssum[r] = 0.f; gl[r] = -1e30f; }

    for (int jt = 0; jt < 16; jt++) {
        int j0 = jt * 2048 + tid;         // 4 columns: j0 + q*512
        float lg0[8], lg1[8], lg2[8], lg3[8];
#pragma unroll
        for (int r = 0; r < 8; r++) { lg0[r] = 0.f; lg1[r] = 0.f; lg2[r] = 0.f; lg3[r] = 0.f; }
        bool v0 = (j0 < VO), v1 = (j0 + 512 < VO), v2 = (j0 + 1024 < VO), v3 = (j0 + 1536 < VO);
        const __hip_bfloat16* p = outT + j0;
        for (int k = 0; k < C3; k++) {
            float w0 = v0 ? __bfloat162float(p[0]) : 0.f;
            float w1 = v1 ? __bfloat162float(p[512]) : 0.f;
            float w2 = v2 ? __bfloat162float(p[1024]) : 0.f;
            float w3 = v3 ? __bfloat162float(p[1536]) : 0.f;
#pragma unroll
            for (int r = 0; r < 8; r++) {
                float cs = c_s[r * C3 + k];
                lg0[r] += cs * w0; lg1[r] += cs * w1; lg2[r] += cs * w2; lg3[r] += cs * w3;
            }
            p += JS;
        }
#pragma unroll
        for (int q = 0; q < 4; q++) {
            int j = j0 + q * 512;
            if (j < VO) {
                float obj = ob[j];
#pragma unroll
                for (int r = 0; r < 8; r++) {
                    float L = (q == 0 ? lg0[r] : q == 1 ? lg1[r] : q == 2 ? lg2[r] : lg3[r]) + obj;
                    if (j == jstar[r]) gl[r] = L;
                    float mn = fmaxf(m[r], L);
                    ssum[r] = ssum[r] * __expf(m[r] - mn) + __expf(L - mn);
                    m[r] = mn;
                }
            }
        }
    }
    // block reductions per row
    for (int r = 0; r < 8; r++) {
        redm[tid] = m[r]; reds[tid] = ssum[r];
        __syncthreads();
        for (int w = 256; w > 0; w >>= 1) {
            if (tid < w) {
                float m1 = redm[tid], m2 = redm[tid + w];
                float mn = fmaxf(m1, m2);
                reds[tid] = reds[tid] * __expf(m1 - mn) + reds[tid + w] * __expf(m2 - mn);
                redm[tid] = mn;
            }
            __syncthreads();
        }
        if (tid == 0) { Mrow[r] = redm[0]; Srow[r] = reds[0]; }
        __syncthreads();
        redm[tid] = gl[r];
        __syncthreads();
        for (int w = 256; w > 0; w >>= 1) {
            if (tid < w) redm[tid] = fmaxf(redm[tid], redm[tid + w]);
            __syncthreads();
        }
        if (tid == 0) glds[r] = redm[0];
        __syncthreads();
    }
    if (tid < 8) {
        int r = tid, row = row0 + r, b = row >> 7, t = row & 127;
        int nt = tgt[b * T + t];
        float genp = 0.f;
        if (nt >= 3 && nt < V) genp = __expf(glds[r] - Mrow[r]) / Srow[r];
        float pg = pgen[row];
        pout[row] = pg * genp + (1.f - pg) * copyp[row];
    }
}

// ---------------- final NLL reduction. grid B, 128 threads
__global__ void nll_k(const float* __restrict__ pout, const int* __restrict__ tlen,
                      float* __restrict__ out) {
    int b = blockIdx.x;
    int t = threadIdx.x;
    __shared__ float red[128];
    float p = pout[b * T + t];
    red[t] = (t < tlen[b]) ? -logf(p + 1e-9f) : 0.f;
    __syncthreads();
    for (int w = 64; w > 0; w >>= 1) { if (t < w) red[t] += red[t + w]; __syncthreads(); }
    if (t == 0) out[b] = red[0];
}

extern "C" void kernel_launch(void* const* d_in, const int* in_sizes, int n_in,
                              void* d_out, int out_size, void* d_ws, size_t ws_size,
                              hipStream_t stream) {
    const int* input_ids = (const int*)d_in[0];
    const int* target_ids = (const int*)d_in[1];
    const int* tlen = (const int*)d_in[3];
    const float* emb = (const float*)d_in[5];
    const float* eWih0f = (const float*)d_in[6],  *eWhh0f = (const float*)d_in[7],  *eb0f = (const float*)d_in[8];
    const float* eWih0b = (const float*)d_in[9],  *eWhh0b = (const float*)d_in[10], *eb0b = (const float*)d_in[11];
    const float* eWih1f = (const float*)d_in[12], *eWhh1f = (const float*)d_in[13], *eb1f = (const float*)d_in[14];
    const float* eWih1b = (const float*)d_in[15], *eWhh1b = (const float*)d_in[16], *eb1b = (const float*)d_in[17];
    const float* dWih0 = (const float*)d_in[18], *dWhh0 = (const float*)d_in[19], *db0 = (const float*)d_in[20];
    const float* dWih1 = (const float*)d_in[21], *dWhh1 = (const float*)d_in[22], *db1 = (const float*)d_in[23];
    const float* Wenc = (const float*)d_in[24], *Wdec = (const float*)d_in[25];
    const float* Wvoc = (const float*)d_in[26], *sW = (const float*)d_in[27], *sb = (const float*)d_in[28];
    const float* ob = (const float*)d_in[29];
    float* out = (float*)d_out;
    (void)ws_size; (void)n_in; (void)in_sizes; (void)out_size;

    // ============ workspace layout (~138 MB total, phase-aliased) ============
    // Region A (98,304,000 B):
    //   phase 1 (pack .. dec_scan):   packed weights [0 .. 23,068,672)
    //   phase 1 (enc gates/scans):    G0f @23,068,672 (33.5M), G0b @56,623,104 (33.5M)
    //   phase 2 (dec gates/attn):     Gd0 @23,068,672 (16.8M), ench @39,845,888 (16.8M),
    //                                 ectx @56,623,104 (4.2M), dctx @60,817,408 (4.2M)
    //   phase 3 (outproj .. vocab):   outT bf16 [0 .. 98,304,000)
    char* A = (char*)d_ws;
    float4* pWhh0f = (float4*)(A + 0);
    float4* pWhh0b = (float4*)(A + 1048576);
    float4* pWhh1f = (float4*)(A + 2097152);
    float4* pWhh1b = (float4*)(A + 3145728);
    float4* pWih0f = (float4*)(A + 4194304);
    float4* pWih0b = (float4*)(A + 4718592);
    float4* pWih1f = (float4*)(A + 5242880);
    float4* pWih1b = (float4*)(A + 7340032);
    float4* pdWih0 = (float4*)(A + 9437184);
    float4* pdWhh0 = (float4*)(A + 10485760);
    float4* pdWih1 = (float4*)(A + 14680064);
    float4* pdWhh1 = (float4*)(A + 18874368);
    float* G0f = (float*)(A + 23068672);
    float* G0b = (float*)(A + 56623104);
    float* Gd0 = (float*)(A + 23068672);            // aliases G0f (dead after enc_scan L1)
    float* ench = (float*)(A + 39845888);           // aliases G0f upper half
    float* ectx = (float*)(A + 56623104);           // aliases G0b
    float* dctx = (float*)(A + 60817408);           // aliases G0b
    __hip_bfloat16* outT = (__hip_bfloat16*)A;      // whole region, after concat_k

    // Region Bh (16,777,216 B): h0f/h0b (enc phase) -> h1d/qe/qd/ew (dec phase)
    char* Bh = A + 98304000;
    float* h0f = (float*)(Bh + 0);
    float* h0b = (float*)(Bh + 8388608);
    float* h1d = (float*)(Bh + 0);                  // aliases h0f (dead after enc1_gates)
    float* qe  = (float*)(Bh + 4194304);
    float* qd  = (float*)(Bh + 8388608);
    float* ew  = (float*)(Bh + 12582912);
    // persistent small buffers
    char* Cr = Bh + 16777216;
    float* h1f = (float*)(Cr + 0);                  // 8,388,608
    float* h1b = (float*)(Cr + 8388608);            // 8,388,608
    float* cc  = (float*)(Cr + 16777216);           // 12,582,912
    float* dec_init = (float*)(Cr + 29360128);      // 65,536
    float* pgen  = (float*)(Cr + 29425664);         // 8,192
    float* copyp = (float*)(Cr + 29433856);         // 8,192
    float* pvec  = (float*)(Cr + 29442048);         // 8,192
    // total: 98,304,000 + 16,777,216 + 29,450,240 = 144,531,456 B (~138 MiB)

    auto pack = [&](const float* W, float4* P, int Hn, int K) {
        int total = Hn * K;
        hipLaunchKernelGGL(pack4_kernel, dim3((total + 255) / 256), dim3(256), 0, stream, W, P, Hn, K);
    };
    pack(eWhh0f, pWhh0f, H, H);
    pack(eWhh0b, pWhh0b, H, H);
    pack(eWhh1f, pWhh1f, H, H);
    pack(eWhh1b, pWhh1b, H, H);
    pack(eWih0f, pWih0f, H, E);
    pack(eWih0b, pWih0b, H, E);
    pack(eWih1f, pWih1f, H, D);
    pack(eWih1b, pWih1b, H, D);
    pack(dWih0, pdWih0, D, E);
    pack(dWhh0, pdWhh0, D, D);
    pack(dWih1, pdWih1, D, D);
    pack(dWhh1, pdWhh1, D, D);

    hipLaunchKernelGGL(enc0_gates, dim3(S * B), dim3(H), 0, stream,
                       input_ids, emb, pWih0f, eb0f, pWih0b, eb0b, G0f, G0b);
    hipLaunchKernelGGL(enc_scan, dim3(32), dim3(H), 0, stream,
                       G0f, G0b, pWhh0f, pWhh0b, h0f, h0b, dec_init);
    hipLaunchKernelGGL(enc1_gates, dim3(S * B), dim3(H), 0, stream,
                       h0f, h0b, pWih1f, eb1f, pWih1b, eb1b, G0f, G0b);
    hipLaunchKernelGGL(enc_scan, dim3(32), dim3(H), 0, stream,
                       G0f, G0b, pWhh1f, pWhh1b, h1f, h1b, dec_init + B * D);
    hipLaunchKernelGGL(dec0_gates, dim3(T * B), dim3(D), 0, stream,
                       target_ids, emb, pdWih0, db0, Gd0);
    hipLaunchKernelGGL(dec_scan, dim3(B), dim3(D), 0, stream,
                       Gd0, pdWhh0, pdWih1, pdWhh1, db1, dec_init, h1d);
    hipLaunchKernelGGL(build_encht, dim3(B * 256), dim3(256), 0, stream, h1f, h1b, ench);
    hipLaunchKernelGGL(qproj, dim3(T * B), dim3(D), 0, stream, h1d, Wenc, Wdec, qe, qd);
    hipLaunchKernelGGL(escore, dim3(B * T), dim3(S), 0, stream, qe, ench, ew);
    hipLaunchKernelGGL(temporal_k, dim3((B * S + 255) / 256), dim3(256), 0, stream, ew);
    hipLaunchKernelGGL(attnctx, dim3(B * T), dim3(S), 0, stream,
                       ew, input_ids, target_ids, h1f, h1b, ectx, copyp);
    hipLaunchKernelGGL(decattn, dim3(B * T), dim3(T), 0, stream, qd, h1d, dctx);
    hipLaunchKernelGGL(concat_k, dim3(B * T), dim3(D), 0, stream,
                       h1d, ectx, dctx, sW, sb, cc, pgen);
    hipLaunchKernelGGL(outprojT_k, dim3((VO + 31) / 32), dim3(256), 0, stream, emb, Wvoc, outT);
    hipLaunchKernelGGL(vocab_k, dim3(B * T / 8), dim3(512), 0, stream,
                       outT, cc, ob, target_ids, pgen, copyp, pvec);
    hipLaunchKernelGGL(nll_k, dim3(B), dim3(T), 0, stream, pvec, tlen, out);
}

// Round 3
// 31081.445 us; speedup vs baseline: 1.7166x; 1.7166x over previous
//
#include <hip/hip_runtime.h>
#include <hip/hip_bf16.h>
#include <math.h>

#define PAD_ID 0
#define UNK_ID 1
#define START_ID 2
#define END_ID 3

constexpr int B = 16, S = 512, T = 128, V = 32000, E = 128, H = 256, D = 512;
constexpr int C3 = 1536;        // 3*D
constexpr int VO = 31997;       // V-3
constexpr int JS = 32000;       // padded col count for outT2

typedef short short8 __attribute__((ext_vector_type(8)));
typedef float f32x4 __attribute__((ext_vector_type(4)));

__device__ __forceinline__ float sigm(float x) { return 1.0f / (1.0f + __expf(-x)); }
__device__ __forceinline__ short bf16s(float x) {
    __hip_bfloat16 h = __float2bfloat16(x);
    return *reinterpret_cast<short*>(&h);
}

// ---------------- weight packing: W[4H][K] -> P[k][u] = float4{W[u][k],W[H+u][k],W[2H+u][k],W[3H+u][k]}
__global__ void pack4_kernel(const float* __restrict__ W, float4* __restrict__ P, int Hn, int K) {
    int i = blockIdx.x * blockDim.x + threadIdx.x;
    if (i >= K * Hn) return;
    int k = i / Hn, u = i - k * Hn;
    float4 v;
    v.x = W[(size_t)(0 * Hn + u) * K + k];
    v.y = W[(size_t)(1 * Hn + u) * K + k];
    v.z = W[(size_t)(2 * Hn + u) * K + k];
    v.w = W[(size_t)(3 * Hn + u) * K + k];
    P[(size_t)k * Hn + u] = v;
}

// ---------------- encoder layer-0 gate preactivations for both directions
__global__ void enc0_gates(const int* __restrict__ ids, const float* __restrict__ emb,
                           const float4* __restrict__ Pf, const float* __restrict__ bf_,
                           const float4* __restrict__ Pb, const float* __restrict__ bb_,
                           float* __restrict__ Gf, float* __restrict__ Gb) {
    int n = blockIdx.x;
    int s = n / B, b = n - s * B;
    int u = threadIdx.x;
    __shared__ float xr[E];
    int tok = ids[b * S + s];
    if (tok >= V) tok = UNK_ID;
    if (u < E) xr[u] = emb[(size_t)tok * E + u];
    __syncthreads();
    float a0 = bf_[0 * H + u], a1 = bf_[1 * H + u], a2 = bf_[2 * H + u], a3 = bf_[3 * H + u];
#pragma unroll 4
    for (int k = 0; k < E; k++) {
        float xv = xr[k]; float4 w = Pf[k * H + u];
        a0 += xv * w.x; a1 += xv * w.y; a2 += xv * w.z; a3 += xv * w.w;
    }
    float* g = Gf + (size_t)n * 4 * H;
    g[0 * H + u] = a0; g[1 * H + u] = a1; g[2 * H + u] = a2; g[3 * H + u] = a3;
    a0 = bb_[0 * H + u]; a1 = bb_[1 * H + u]; a2 = bb_[2 * H + u]; a3 = bb_[3 * H + u];
#pragma unroll 4
    for (int k = 0; k < E; k++) {
        float xv = xr[k]; float4 w = Pb[k * H + u];
        a0 += xv * w.x; a1 += xv * w.y; a2 += xv * w.z; a3 += xv * w.w;
    }
    g = Gb + (size_t)n * 4 * H;
    g[0 * H + u] = a0; g[1 * H + u] = a1; g[2 * H + u] = a2; g[3 * H + u] = a3;
}

// ---------------- encoder layer-1 gate preactivations (input = concat(h0f,h0b))
__global__ void enc1_gates(const float* __restrict__ h0f, const float* __restrict__ h0b,
                           const float4* __restrict__ Pf, const float* __restrict__ bf_,
                           const float4* __restrict__ Pb, const float* __restrict__ bb_,
                           float* __restrict__ Gf, float* __restrict__ Gb) {
    int n = blockIdx.x;      // s*B+b
    int u = threadIdx.x;     // 256
    __shared__ float xr[D];
    xr[u] = h0f[(size_t)n * H + u];
    xr[H + u] = h0b[(size_t)n * H + u];
    __syncthreads();
    float a0 = bf_[0 * H + u], a1 = bf_[1 * H + u], a2 = bf_[2 * H + u], a3 = bf_[3 * H + u];
#pragma unroll 4
    for (int k = 0; k < D; k++) {
        float xv = xr[k]; float4 w = Pf[k * H + u];
        a0 += xv * w.x; a1 += xv * w.y; a2 += xv * w.z; a3 += xv * w.w;
    }
    float* g = Gf + (size_t)n * 4 * H;
    g[0 * H + u] = a0; g[1 * H + u] = a1; g[2 * H + u] = a2; g[3 * H + u] = a3;
    a0 = bb_[0 * H + u]; a1 = bb_[1 * H + u]; a2 = bb_[2 * H + u]; a3 = bb_[3 * H + u];
#pragma unroll 4
    for (int k = 0; k < D; k++) {
        float xv = xr[k]; float4 w = Pb[k * H + u];
        a0 += xv * w.x; a1 += xv * w.y; a2 += xv * w.z; a3 += xv * w.w;
    }
    g = Gb + (size_t)n * 4 * H;
    g[0 * H + u] = a0; g[1 * H + u] = a1; g[2 * H + u] = a2; g[3 * H + u] = a3;
}

// ---------------- bidirectional encoder scan for one layer. grid 32 = b*2+dir, 256 threads.
__global__ void enc_scan(const float* __restrict__ Gf, const float* __restrict__ Gb,
                         const float4* __restrict__ Pf, const float4* __restrict__ Pb,
                         float* __restrict__ hof, float* __restrict__ hob,
                         float* __restrict__ hfin /* [B][2H] */) {
    int blk = blockIdx.x;
    int dirb = blk & 1, b = blk >> 1;
    int u = threadIdx.x;
    const float* G = dirb ? Gb : Gf;
    const float4* P = dirb ? Pb : Pf;
    float* ho = dirb ? hob : hof;
    __shared__ float hs[H];
    float c = 0.f, h = 0.f;
    hs[u] = 0.f;
    __syncthreads();
    for (int step = 0; step < S; step++) {
        int s = dirb ? (S - 1 - step) : step;
        const float* g = G + ((size_t)(s * B + b)) * (4 * H);
        float a0 = g[u], a1 = g[H + u], a2 = g[2 * H + u], a3 = g[3 * H + u];
#pragma unroll 4
        for (int k = 0; k < H; k++) {
            float hk = hs[k]; float4 w = P[k * H + u];
            a0 += hk * w.x; a1 += hk * w.y; a2 += hk * w.z; a3 += hk * w.w;
        }
        float ig = sigm(a0), fg = sigm(a1), gg = tanhf(a2), og = sigm(a3);
        c = fg * c + ig * gg;
        h = og * tanhf(c);
        __syncthreads();
        hs[u] = h;
        ho[((size_t)(s * B + b)) * H + u] = h;
        __syncthreads();
    }
    hfin[b * (2 * H) + dirb * H + u] = h;
}

// ---------------- decoder layer-0 input gates (teacher tokens). grid T*B (n=t*B+b), 512 thr.
__global__ void dec0_gates(const int* __restrict__ tgt, const float* __restrict__ emb,
                           const float4* __restrict__ P, const float* __restrict__ bias,
                           float* __restrict__ G) {
    int n = blockIdx.x;
    int t = n / B, b = n - t * B;
    int u = threadIdx.x;
    __shared__ float xr[E];
    int tok;
    if (t == 0) tok = START_ID;
    else { tok = tgt[b * T + (t - 1)]; if (tok >= V) tok = UNK_ID; }
    if (u < E) xr[u] = emb[(size_t)tok * E + u];
    __syncthreads();
    float a0 = bias[0 * D + u], a1 = bias[1 * D + u], a2 = bias[2 * D + u], a3 = bias[3 * D + u];
#pragma unroll 4
    for (int k = 0; k < E; k++) {
        float xv = xr[k]; float4 w = P[k * D + u];
        a0 += xv * w.x; a1 += xv * w.y; a2 += xv * w.z; a3 += xv * w.w;
    }
    float* g = G + (size_t)n * 4 * D;
    g[0 * D + u] = a0; g[1 * D + u] = a1; g[2 * D + u] = a2; g[3 * D + u] = a3;
}

// ---------------- decoder 2-layer scan. grid B=16 blocks, 512 threads (u = hidden unit).
__global__ void __launch_bounds__(512) dec_scan(
        const float* __restrict__ G0, const float4* __restrict__ P0,
        const float4* __restrict__ P1i, const float4* __restrict__ P1h,
        const float* __restrict__ b1, const float* __restrict__ hinit,
        float* __restrict__ h1out) {
    int b = blockIdx.x;
    int u = threadIdx.x;
    __shared__ float hs0[D], hs1[D];
    float c0 = 0.f, c1 = 0.f;
    hs0[u] = hinit[b * D + u];
    hs1[u] = hinit[B * D + b * D + u];
    float bi0 = b1[u], bi1 = b1[D + u], bi2 = b1[2 * D + u], bi3 = b1[3 * D + u];
    __syncthreads();
    for (int t = 0; t < T; t++) {
        const float* g = G0 + ((size_t)(t * B + b)) * (4 * D);
        float a0 = g[u], a1 = g[D + u], a2 = g[2 * D + u], a3 = g[3 * D + u];
#pragma unroll 4
        for (int k = 0; k < D; k++) {
            float hk = hs0[k]; float4 w = P0[k * D + u];
            a0 += hk * w.x; a1 += hk * w.y; a2 += hk * w.z; a3 += hk * w.w;
        }
        float ig = sigm(a0), fg = sigm(a1), gg = tanhf(a2), og = sigm(a3);
        c0 = fg * c0 + ig * gg;
        float h0n = og * tanhf(c0);
        __syncthreads();
        hs0[u] = h0n;
        __syncthreads();
        a0 = bi0; a1 = bi1; a2 = bi2; a3 = bi3;
#pragma unroll 4
        for (int k = 0; k < D; k++) {
            float hk = hs0[k]; float4 w = P1i[k * D + u];
            a0 += hk * w.x; a1 += hk * w.y; a2 += hk * w.z; a3 += hk * w.w;
        }
#pragma unroll 4
        for (int k = 0; k < D; k++) {
            float hk = hs1[k]; float4 w = P1h[k * D + u];
            a0 += hk * w.x; a1 += hk * w.y; a2 += hk * w.z; a3 += hk * w.w;
        }
        ig = sigm(a0); fg = sigm(a1); gg = tanhf(a2); og = sigm(a3);
        c1 = fg * c1 + ig * gg;
        float h1n = og * tanhf(c1);
        __syncthreads();
        hs1[u] = h1n;
        h1out[((size_t)(t * B + b)) * D + u] = h1n;
        __syncthreads();
    }
}

// ---------------- transpose enc hidden to [b][k(512)][s] for coalesced score dots
__global__ void build_encht(const float* __restrict__ h1f, const float* __restrict__ h1b,
                            float* __restrict__ et) {
    int blk = blockIdx.x;                 // b*256 + kt*16 + st
    int b = blk >> 8, rem = blk & 255;
    int kt = rem >> 4, st = rem & 15;
    int c = threadIdx.x & 31, r = threadIdx.x >> 5;   // r in 0..7
    __shared__ float tile[32][33];
#pragma unroll
    for (int i = 0; i < 4; i++) {
        int sl = r + i * 8;               // s_local
        int s = st * 32 + sl;
        int k = kt * 32 + c;              // lane-contiguous over k
        float v = (k < H) ? h1f[((size_t)(s * B + b)) * H + k]
                          : h1b[((size_t)(s * B + b)) * H + (k - H)];
        tile[c][sl] = v;                  // tile[k_local][s_local]
    }
    __syncthreads();
#pragma unroll
    for (int i = 0; i < 4; i++) {
        int kl = r + i * 8;
        et[(size_t)b * D * S + (size_t)(kt * 32 + kl) * S + st * 32 + c] = tile[kl][c];
    }
}

// ---------------- q projections. grid T*B (n=t*B+b), 512 threads
__global__ void qproj(const float* __restrict__ h1d, const float* __restrict__ Wenc,
                      const float* __restrict__ Wdec, float* __restrict__ qe, float* __restrict__ qd) {
    int n = blockIdx.x;
    int o = threadIdx.x;
    __shared__ float hr[D];
    hr[o] = h1d[(size_t)n * D + o];
    __syncthreads();
    float ae = 0.f, ad = 0.f;
#pragma unroll 4
    for (int k = 0; k < D; k++) {
        float hk = hr[k];
        ae += hk * Wenc[k * D + o];
        ad += hk * Wdec[k * D + o];
    }
    qe[(size_t)n * D + o] = ae;
    qd[(size_t)n * D + o] = ad;
}

// ---------------- e = exp(min(score,30)). grid B*T (bt=b*T+t), 512 threads (s)
__global__ void escore(const float* __restrict__ qe, const float* __restrict__ et,
                       float* __restrict__ ew) {
    int bt = blockIdx.x;
    int b = bt / T, t = bt - b * T;
    int sx = threadIdx.x;
    __shared__ float q[D];
    q[sx] = qe[((size_t)(t * B + b)) * D + sx];
    __syncthreads();
    float acc = 0.f;
    const float* eb = et + (size_t)b * D * S + sx;
#pragma unroll 4
    for (int k = 0; k < D; k++) { acc += q[k] * eb[0]; eb += S; }
    acc = fminf(acc, 30.0f);
    ew[(size_t)bt * S + sx] = __expf(acc);
}

// ---------------- temporal normalization (prefix over t, in place)
__global__ void temporal_k(float* __restrict__ ew) {
    int i = blockIdx.x * blockDim.x + threadIdx.x;
    if (i >= B * S) return;
    int b = i / S, sx = i - b * S;
    float cum = 0.f;
    for (int t = 0; t < T; t++) {
        size_t idx = ((size_t)(b * T + t)) * S + sx;
        float v = ew[idx];
        ew[idx] = v / (t == 0 ? 1.0f : (cum + 1e-8f));
        cum += v;
    }
}

// ---------------- attention softmax over s + enc context + copy prob. grid B*T, 512 thr
__global__ void attnctx(const float* __restrict__ ew, const int* __restrict__ ids,
                        const int* __restrict__ tgt,
                        const float* __restrict__ h1f, const float* __restrict__ h1b,
                        float* __restrict__ ectx, float* __restrict__ copyp) {
    int bt = blockIdx.x;
    int b = bt / T, t = bt - b * T;
    int tid = threadIdx.x;
    __shared__ float aw[S];
    __shared__ float red[512];
    float v = ew[(size_t)bt * S + tid];
    int tok = ids[b * S + tid];
    bool pad = (tok == PAD_ID);
    float vm = pad ? -INFINITY : v;
    red[tid] = vm; __syncthreads();
    for (int w = 256; w > 0; w >>= 1) { if (tid < w) red[tid] = fmaxf(red[tid], red[tid + w]); __syncthreads(); }
    float m = red[0]; __syncthreads();
    float ex = pad ? 0.f : __expf(vm - m);
    red[tid] = ex; __syncthreads();
    for (int w = 256; w > 0; w >>= 1) { if (tid < w) red[tid] += red[tid + w]; __syncthreads(); }
    float Z = red[0]; __syncthreads();
    float a = ex / Z;
    aw[tid] = a;
    int nt = tgt[b * T + t];
    red[tid] = (tok == nt) ? a : 0.f; __syncthreads();
    for (int w = 256; w > 0; w >>= 1) { if (tid < w) red[tid] += red[tid + w]; __syncthreads(); }
    if (tid == 0) copyp[bt] = red[0];
    __syncthreads();
    int d = tid;
    const float* hp = (d < H) ? (h1f + (size_t)b * H + d) : (h1b + (size_t)b * H + (d - H));
    float acc = 0.f;
#pragma unroll 4
    for (int s2 = 0; s2 < S; s2++) { acc += aw[s2] * hp[0]; hp += B * H; }
    ectx[(size_t)bt * D + d] = acc;
}

// ---------------- intra-decoder attention. grid B*T, 128 threads
__global__ void decattn(const float* __restrict__ qd, const float* __restrict__ h1d,
                        float* __restrict__ dctx) {
    int bt = blockIdx.x;
    int b = bt / T, t = bt - b * T;
    int tid = threadIdx.x;
    __shared__ float q[D];
    __shared__ float wl[T];
    __shared__ float red[128];
    for (int i = tid; i < D; i += 128) q[i] = qd[((size_t)(t * B + b)) * D + i];
    __syncthreads();
    float sc = -INFINITY;
    if (tid < t) {
        const float* hu = h1d + ((size_t)(tid * B + b)) * D;
        float a = 0.f;
#pragma unroll 4
        for (int k = 0; k < D; k++) a += q[k] * hu[k];
        sc = a;
    }
    red[tid] = sc; __syncthreads();
    for (int w = 64; w > 0; w >>= 1) { if (tid < w) red[tid] = fmaxf(red[tid], red[tid + w]); __syncthreads(); }
    float m = red[0]; __syncthreads();
    float ex = (tid < t) ? __expf(sc - m) : 0.f;
    red[tid] = ex; __syncthreads();
    for (int w = 64; w > 0; w >>= 1) { if (tid < w) red[tid] += red[tid + w]; __syncthreads(); }
    float Z = red[0]; __syncthreads();
    wl[tid] = (t > 0) ? (ex / Z) : 0.f;
    __syncthreads();
    for (int d = tid; d < D; d += 128) {
        float acc = 0.f;
        for (int u = 0; u < t; u++) acc += wl[u] * h1d[((size_t)(u * B + b)) * D + d];
        dctx[(size_t)bt * D + d] = acc;
    }
}

// ---------------- concat + p_gen. grid B*T, 512 threads
__global__ void concat_k(const float* __restrict__ h1d, const float* __restrict__ ectx,
                         const float* __restrict__ dctx, const float* __restrict__ sW,
                         const float* __restrict__ sb, float* __restrict__ cc,
                         float* __restrict__ pgen) {
    int bt = blockIdx.x;
    int b = bt / T, t = bt - b * T;
    int d = threadIdx.x;
    __shared__ float red[512];
    float v0 = h1d[((size_t)(t * B + b)) * D + d];
    float v1 = ectx[(size_t)bt * D + d];
    float v2 = dctx[(size_t)bt * D + d];
    float* c = cc + (size_t)bt * C3;
    c[d] = v0; c[D + d] = v1; c[2 * D + d] = v2;
    red[d] = v0 * sW[d] + v1 * sW[D + d] + v2 * sW[2 * D + d];
    __syncthreads();
    for (int w = 256; w > 0; w >>= 1) { if (d < w) red[d] += red[d + w]; __syncthreads(); }
    if (d == 0) pgen[bt] = 1.f / (1.f + __expf(-(red[0] + sb[0])));
}

// ---------------- out_proj, packed-k layout for MFMA B-fragments.
// outT2 element (k, j) stored at (k>>3)*JS*8 + j*8 + (k&7), bf16.
// grid 1000 blocks (32 j each), 256 threads: jl = tid&31, oq = tid>>5 (octet quarter)
__global__ void outprojT_k(const float* __restrict__ emb, const float* __restrict__ Wvoc,
                           __hip_bfloat16* __restrict__ outT2) {
    int j0 = blockIdx.x * 32;
    int jl = threadIdx.x & 31, oq = threadIdx.x >> 5;   // oq in 0..7
    __shared__ float er[32][E + 1];                      // +1 pad
    for (int i = threadIdx.x; i < 32 * E; i += 256) {
        int jj = i >> 7, e = i & 127;
        int j = j0 + jj;
        er[jj][e] = (j < VO) ? emb[(size_t)(3 + j) * E + e] : 0.f;
    }
    __syncthreads();
    int j = j0 + jl;
#pragma unroll 1
    for (int i = 0; i < 24; i++) {
        int o = oq * 24 + i;                             // octet index 0..191
        int k0 = o * 8;
        float acc[8];
#pragma unroll
        for (int kk = 0; kk < 8; kk++) acc[kk] = 0.f;
#pragma unroll 4
        for (int e = 0; e < E; e++) {
            float x = er[jl][e];
            float4 w0 = *(const float4*)(Wvoc + (size_t)e * C3 + k0);
            float4 w1 = *(const float4*)(Wvoc + (size_t)e * C3 + k0 + 4);
            acc[0] += x * w0.x; acc[1] += x * w0.y; acc[2] += x * w0.z; acc[3] += x * w0.w;
            acc[4] += x * w1.x; acc[5] += x * w1.y; acc[6] += x * w1.z; acc[7] += x * w1.w;
        }
        short8 v;
#pragma unroll
        for (int kk = 0; kk < 8; kk++) v[kk] = bf16s(tanhf(acc[kk]));
        *reinterpret_cast<short8*>((char*)outT2 + ((size_t)o * JS + j) * 16) = v;
    }
}

// ---------------- vocab GEMM via MFMA + fused online softmax partials.
// grid 256 = q(0..3)*64 + rb(0..63). 512 threads = 8 waves (wr = wid>>2, wc = wid&3).
// Block: rows rb*32..+31 (M_tile=32), cols quarter q (8192 wide), K = 1536.
__global__ void __launch_bounds__(512) vocab_mfma(
        const __hip_bfloat16* __restrict__ outT2, const float* __restrict__ cc,
        const float* __restrict__ ob, const int* __restrict__ tgt,
        float* __restrict__ pbuf) {
    __shared__ __align__(16) short As[32 * 1536];        // bf16 A tile, chunk-XOR swizzled
    __shared__ float wm[8][32], ws_[8][32], wg[8][32];
    __shared__ int jstar_s[32];
    int bid = blockIdx.x;
    int rb = bid & 63, q = bid >> 6;
    int row0 = rb * 32;
    int tid = threadIdx.x;

    // ---- stage A: cc rows (fp32) -> bf16 LDS, 16B chunks XOR-swizzled by row&7
    {
        int r = tid >> 4, cpos = tid & 15;
        const float* src = cc + (size_t)(row0 + r) * C3;
        int r7 = r & 7;
        short* dst = As + r * C3;
#pragma unroll
        for (int ii = 0; ii < 12; ii++) {
            int c = ii * 16 + cpos;                      // chunk 0..191 (8 bf16 each)
            float4 f0 = *(const float4*)(src + c * 8);
            float4 f1 = *(const float4*)(src + c * 8 + 4);
            short8 v;
            v[0] = bf16s(f0.x); v[1] = bf16s(f0.y); v[2] = bf16s(f0.z); v[3] = bf16s(f0.w);
            v[4] = bf16s(f1.x); v[5] = bf16s(f1.y); v[6] = bf16s(f1.z); v[7] = bf16s(f1.w);
            *reinterpret_cast<short8*>(dst + ((c ^ r7) << 3)) = v;
        }
    }
    if (tid < 32) {
        int nt = tgt[row0 + tid];                        // row = b*T+t == flat index
        int ix = nt - 3;
        ix = ix < 0 ? 0 : (ix > VO - 1 ? VO - 1 : ix);
        jstar_s[tid] = ix;
    }
    __syncthreads();

    int lane = tid & 63, wid = tid >> 6;
    int wr = wid >> 2, wc = wid & 3;
    int cl = lane & 15, g = lane >> 4;                   // g = k-octet group
    int rowA = wr * 16 + cl;
    const short* Abase = As + rowA * C3;
    int r7 = rowA & 7;
    int jst[4];
    float m[4], sacc[4], gl[4];
#pragma unroll
    for (int i = 0; i < 4; i++) {
        jst[i] = jstar_s[wr * 16 + g * 4 + i];
        m[i] = -1e30f; sacc[i] = 0.f; gl[i] = -1e30f;
    }

    int jb0 = q * 8192;
    int jqend = (jb0 + 8192 < VO) ? jb0 + 8192 : VO;
    int nmt = (jqend - jb0 + 127) >> 7;                  // 128-col macro-tiles
    for (int ti = 0; ti < nmt; ti++) {
        int jA = jb0 + ti * 128 + wc * 32 + cl;
        const char* pB = (const char*)outT2 + ((size_t)g * JS + jA) * 16;
        f32x4 acc0 = {0.f, 0.f, 0.f, 0.f}, acc1 = {0.f, 0.f, 0.f, 0.f};
#pragma unroll
        for (int s = 0; s < 48; s++) {
            short8 a = *reinterpret_cast<const short8*>(Abase + (((s * 4 + g) ^ r7) << 3));
            short8 b0 = *reinterpret_cast<const short8*>(pB + (size_t)s * (4 * JS * 16));
            short8 b1 = *reinterpret_cast<const short8*>(pB + (size_t)s * (4 * JS * 16) + 256);
            acc0 = __builtin_amdgcn_mfma_f32_16x16x32_bf16(a, b0, acc0, 0, 0, 0);
            acc1 = __builtin_amdgcn_mfma_f32_16x16x32_bf16(a, b1, acc1, 0, 0, 0);
        }
#pragma unroll
        for (int X = 0; X < 2; X++) {
            int j = jA + X * 16;
            if (j < jqend) {
                float obj = ob[j];
#pragma unroll
                for (int i = 0; i < 4; i++) {
                    float L = (X ? acc1[i] : acc0[i]) + obj;
                    if (j == jst[i]) gl[i] = L;
                    float mn = fmaxf(m[i], L);
                    sacc[i] = sacc[i] * __expf(m[i] - mn) + __expf(L - mn);
                    m[i] = mn;
                }
            }
        }
    }

    // ---- in-wave butterfly over the 16 col-lanes sharing the same rows
#pragma unroll
    for (int i = 0; i < 4; i++) {
        for (int mask = 1; mask < 16; mask <<= 1) {
            float om = __shfl_xor(m[i], mask);
            float os = __shfl_xor(sacc[i], mask);
            float mn = fmaxf(m[i], om);
            sacc[i] = sacc[i] * __expf(m[i] - mn) + os * __expf(om - mn);
            m[i] = mn;
            gl[i] = fmaxf(gl[i], __shfl_xor(gl[i], mask));
        }
    }
    if (cl == 0) {
#pragma unroll
        for (int i = 0; i < 4; i++) {
            int rl = wr * 16 + g * 4 + i;
            wm[wid][rl] = m[i]; ws_[wid][rl] = sacc[i]; wg[wid][rl] = gl[i];
        }
    }
    __syncthreads();
    if (tid < 32) {
        float M = -1e30f, SS = 0.f, GL = -1e30f;
        int w0 = (tid >> 4) * 4;
#pragma unroll
        for (int w = 0; w < 4; w++) {
            float mq = wm[w0 + w][tid], sq = ws_[w0 + w][tid], gq = wg[w0 + w][tid];
            float mn = fmaxf(M, mq);
            SS = SS * __expf(M - mn) + sq * __expf(mq - mn);
            M = mn;
            GL = fmaxf(GL, gq);
        }
        float* o = pbuf + ((size_t)bid * 32 + tid) * 4;
        o[0] = M; o[1] = SS; o[2] = GL;
    }
}

// ---------------- combine quarter-partials + pointer mix + NLL. grid B, 128 threads.
__global__ void combine_nll_k(const float* __restrict__ pbuf, const int* __restrict__ tgt,
                              const float* __restrict__ pgen, const float* __restrict__ copyp,
                              const int* __restrict__ tlen, float* __restrict__ out) {
    int b = blockIdx.x, t = threadIdx.x;
    int row = b * T + t;
    int rb = row >> 5, r = row & 31;
    float M = -1e30f, SS = 0.f, GL = -1e30f;
#pragma unroll
    for (int q = 0; q < 4; q++) {
        const float* p = pbuf + ((size_t)(q * 64 + rb) * 32 + r) * 4;
        float mq = p[0], sq = p[1], gq = p[2];
        float mn = fmaxf(M, mq);
        SS = SS * __expf(M - mn) + sq * __expf(mq - mn);
        M = mn;
        GL = fmaxf(GL, gq);
    }
    int nt = tgt[row];
    float genp = (nt >= 3 && nt < V) ? __expf(GL - M) / SS : 0.f;
    float pg = pgen[row];
    float p = pg * genp + (1.f - pg) * copyp[row];
    __shared__ float red[128];
    red[t] = (t < tlen[b]) ? -logf(p + 1e-9f) : 0.f;
    __syncthreads();
    for (int w = 64; w > 0; w >>= 1) { if (t < w) red[t] += red[t + w]; __syncthreads(); }
    if (t == 0) out[b] = red[0];
}

extern "C" void kernel_launch(void* const* d_in, const int* in_sizes, int n_in,
                              void* d_out, int out_size, void* d_ws, size_t ws_size,
                              hipStream_t stream) {
    const int* input_ids = (const int*)d_in[0];
    const int* target_ids = (const int*)d_in[1];
    const int* tlen = (const int*)d_in[3];
    const float* emb = (const float*)d_in[5];
    const float* eWih0f = (const float*)d_in[6],  *eWhh0f = (const float*)d_in[7],  *eb0f = (const float*)d_in[8];
    const float* eWih0b = (const float*)d_in[9],  *eWhh0b = (const float*)d_in[10], *eb0b = (const float*)d_in[11];
    const float* eWih1f = (const float*)d_in[12], *eWhh1f = (const float*)d_in[13], *eb1f = (const float*)d_in[14];
    const float* eWih1b = (const float*)d_in[15], *eWhh1b = (const float*)d_in[16], *eb1b = (const float*)d_in[17];
    const float* dWih0 = (const float*)d_in[18], *dWhh0 = (const float*)d_in[19], *db0 = (const float*)d_in[20];
    const float* dWih1 = (const float*)d_in[21], *dWhh1 = (const float*)d_in[22], *db1 = (const float*)d_in[23];
    const float* Wenc = (const float*)d_in[24], *Wdec = (const float*)d_in[25];
    const float* Wvoc = (const float*)d_in[26], *sW = (const float*)d_in[27], *sb = (const float*)d_in[28];
    const float* ob = (const float*)d_in[29];
    float* out = (float*)d_out;
    (void)ws_size; (void)n_in; (void)in_sizes; (void)out_size;

    // ============ workspace layout (~138 MB, phase-aliased; same as passing R1) ============
    char* A = (char*)d_ws;
    float4* pWhh0f = (float4*)(A + 0);
    float4* pWhh0b = (float4*)(A + 1048576);
    float4* pWhh1f = (float4*)(A + 2097152);
    float4* pWhh1b = (float4*)(A + 3145728);
    float4* pWih0f = (float4*)(A + 4194304);
    float4* pWih0b = (float4*)(A + 4718592);
    float4* pWih1f = (float4*)(A + 5242880);
    float4* pWih1b = (float4*)(A + 7340032);
    float4* pdWih0 = (float4*)(A + 9437184);
    float4* pdWhh0 = (float4*)(A + 10485760);
    float4* pdWih1 = (float4*)(A + 14680064);
    float4* pdWhh1 = (float4*)(A + 18874368);
    float* G0f = (float*)(A + 23068672);
    float* G0b = (float*)(A + 56623104);
    float* Gd0 = (float*)(A + 23068672);            // aliases G0f (dead after enc_scan L1)
    float* ench = (float*)(A + 39845888);           // aliases G0f upper half
    float* ectx = (float*)(A + 56623104);           // aliases G0b
    float* dctx = (float*)(A + 60817408);           // aliases G0b
    __hip_bfloat16* outT2 = (__hip_bfloat16*)A;     // whole region (98,304,000 B), after concat_k

    char* Bh = A + 98304000;
    float* h0f = (float*)(Bh + 0);
    float* h0b = (float*)(Bh + 8388608);
    float* h1d = (float*)(Bh + 0);                  // aliases h0f (dead after enc1_gates)
    float* qe  = (float*)(Bh + 4194304);
    float* qd  = (float*)(Bh + 8388608);
    float* ew  = (float*)(Bh + 12582912);
    char* Cr = Bh + 16777216;
    float* h1f = (float*)(Cr + 0);                  // 8,388,608
    float* h1b = (float*)(Cr + 8388608);            // 8,388,608
    float* cc  = (float*)(Cr + 16777216);           // 12,582,912
    float* dec_init = (float*)(Cr + 29360128);      // 65,536
    float* pgen  = (float*)(Cr + 29425664);         // 8,192
    float* copyp = (float*)(Cr + 29433856);         // 8,192
    float* pbuf  = (float*)(Cr + 29442048);         // 131,072 (256 blocks × 32 rows × 4 f32)
    // total: 98,304,000 + 16,777,216 + 29,573,120 = 144,654,336 B (~138 MiB)

    auto pack = [&](const float* W, float4* P, int Hn, int K) {
        int total = Hn * K;
        hipLaunchKernelGGL(pack4_kernel, dim3((total + 255) / 256), dim3(256), 0, stream, W, P, Hn, K);
    };
    pack(eWhh0f, pWhh0f, H, H);
    pack(eWhh0b, pWhh0b, H, H);
    pack(eWhh1f, pWhh1f, H, H);
    pack(eWhh1b, pWhh1b, H, H);
    pack(eWih0f, pWih0f, H, E);
    pack(eWih0b, pWih0b, H, E);
    pack(eWih1f, pWih1f, H, D);
    pack(eWih1b, pWih1b, H, D);
    pack(dWih0, pdWih0, D, E);
    pack(dWhh0, pdWhh0, D, D);
    pack(dWih1, pdWih1, D, D);
    pack(dWhh1, pdWhh1, D, D);

    hipLaunchKernelGGL(enc0_gates, dim3(S * B), dim3(H), 0, stream,
                       input_ids, emb, pWih0f, eb0f, pWih0b, eb0b, G0f, G0b);
    hipLaunchKernelGGL(enc_scan, dim3(32), dim3(H), 0, stream,
                       G0f, G0b, pWhh0f, pWhh0b, h0f, h0b, dec_init);
    hipLaunchKernelGGL(enc1_gates, dim3(S * B), dim3(H), 0, stream,
                       h0f, h0b, pWih1f, eb1f, pWih1b, eb1b, G0f, G0b);
    hipLaunchKernelGGL(enc_scan, dim3(32), dim3(H), 0, stream,
                       G0f, G0b, pWhh1f, pWhh1b, h1f, h1b, dec_init + B * D);
    hipLaunchKernelGGL(dec0_gates, dim3(T * B), dim3(D), 0, stream,
                       target_ids, emb, pdWih0, db0, Gd0);
    hipLaunchKernelGGL(dec_scan, dim3(B), dim3(D), 0, stream,
                       Gd0, pdWhh0, pdWih1, pdWhh1, db1, dec_init, h1d);
    hipLaunchKernelGGL(build_encht, dim3(B * 256), dim3(256), 0, stream, h1f, h1b, ench);
    hipLaunchKernelGGL(qproj, dim3(T * B), dim3(D), 0, stream, h1d, Wenc, Wdec, qe, qd);
    hipLaunchKernelGGL(escore, dim3(B * T), dim3(S), 0, stream, qe, ench, ew);
    hipLaunchKernelGGL(temporal_k, dim3((B * S + 255) / 256), dim3(256), 0, stream, ew);
    hipLaunchKernelGGL(attnctx, dim3(B * T), dim3(S), 0, stream,
                       ew, input_ids, target_ids, h1f, h1b, ectx, copyp);
    hipLaunchKernelGGL(decattn, dim3(B * T), dim3(T), 0, stream, qd, h1d, dctx);
    hipLaunchKernelGGL(concat_k, dim3(B * T), dim3(D), 0, stream,
                       h1d, ectx, dctx, sW, sb, cc, pgen);
    hipLaunchKernelGGL(outprojT_k, dim3(1000), dim3(256), 0, stream, emb, Wvoc, outT2);
    hipLaunchKernelGGL(vocab_mfma, dim3(256), dim3(512), 0, stream,
                       outT2, cc, ob, target_ids, pbuf);
    hipLaunchKernelGGL(combine_nll_k, dim3(B), dim3(T), 0, stream,
                       pbuf, target_ids, pgen, copyp, tlen, out);
}

// Round 4
// 19680.420 us; speedup vs baseline: 2.7111x; 1.5793x over previous
//
#include <hip/hip_runtime.h>
#include <hip/hip_bf16.h>
#include <math.h>

#define PAD_ID 0
#define UNK_ID 1
#define START_ID 2
#define END_ID 3

constexpr int B = 16, S = 512, T = 128, V = 32000, E = 128, H = 256, D = 512;
constexpr int C3 = 1536;        // 3*D
constexpr int VO = 31997;       // V-3
constexpr int JS = 32000;       // padded col count for outT2
constexpr int NBLK_DEC = 128;   // decoder persistent blocks (u-slice = 4)

typedef short short8 __attribute__((ext_vector_type(8)));
typedef float f32x4 __attribute__((ext_vector_type(4)));

__device__ __forceinline__ float sigm(float x) { return 1.0f / (1.0f + __expf(-x)); }
__device__ __forceinline__ short bf16s(float x) {
    __hip_bfloat16 h = __float2bfloat16(x);
    return *reinterpret_cast<short*>(&h);
}
__device__ __forceinline__ float bflo(unsigned int u) { return __uint_as_float(u << 16); }
__device__ __forceinline__ float bfhi(unsigned int u) { return __uint_as_float(u & 0xffff0000u); }

// ---------------- weight packing: W[4H][K] -> P[k][u] = float4 of 4 gates (f32, for gate kernels)
__global__ void pack4_kernel(const float* __restrict__ W, float4* __restrict__ P, int Hn, int K) {
    int i = blockIdx.x * blockDim.x + threadIdx.x;
    if (i >= K * Hn) return;
    int k = i / Hn, u = i - k * Hn;
    float4 v;
    v.x = W[(size_t)(0 * Hn + u) * K + k];
    v.y = W[(size_t)(1 * Hn + u) * K + k];
    v.z = W[(size_t)(2 * Hn + u) * K + k];
    v.w = W[(size_t)(3 * Hn + u) * K + k];
    P[(size_t)k * Hn + u] = v;
}

// ---------------- encoder Whh pack: W[4H][H] -> P[k][u][g] bf16  (i = (k*256+u)*4+g)
__global__ void packenc_k(const float* __restrict__ W, ushort* __restrict__ P) {
    int i = blockIdx.x * blockDim.x + threadIdx.x;
    if (i >= H * H * 4) return;
    int g = i & 3, u = (i >> 2) & 255, k = i >> 10;
    P[i] = (ushort)bf16s(W[(size_t)(g * H + u) * H + k]);
}

// ---------------- decoder weight pack: W[4D][D] -> P[u][g][k] bf16 (i = ((u*4+g)*512)+k)
__global__ void packdec_k(const float* __restrict__ W, ushort* __restrict__ P) {
    int i = blockIdx.x * blockDim.x + threadIdx.x;
    if (i >= D * D * 4) return;
    int k = i & 511, g = (i >> 9) & 3, u = i >> 11;
    P[i] = (ushort)bf16s(W[(size_t)(g * D + u) * D + k]);
}

// ---------------- encoder layer-0 gate preactivations for both directions
__global__ void enc0_gates(const int* __restrict__ ids, const float* __restrict__ emb,
                           const float4* __restrict__ Pf, const float* __restrict__ bf_,
                           const float4* __restrict__ Pb, const float* __restrict__ bb_,
                           float* __restrict__ Gf, float* __restrict__ Gb) {
    int n = blockIdx.x;
    int s = n / B, b = n - s * B;
    int u = threadIdx.x;
    __shared__ float xr[E];
    int tok = ids[b * S + s];
    if (tok >= V) tok = UNK_ID;
    if (u < E) xr[u] = emb[(size_t)tok * E + u];
    __syncthreads();
    float a0 = bf_[0 * H + u], a1 = bf_[1 * H + u], a2 = bf_[2 * H + u], a3 = bf_[3 * H + u];
#pragma unroll 4
    for (int k = 0; k < E; k++) {
        float xv = xr[k]; float4 w = Pf[k * H + u];
        a0 += xv * w.x; a1 += xv * w.y; a2 += xv * w.z; a3 += xv * w.w;
    }
    float* g = Gf + (size_t)n * 4 * H;
    g[0 * H + u] = a0; g[1 * H + u] = a1; g[2 * H + u] = a2; g[3 * H + u] = a3;
    a0 = bb_[0 * H + u]; a1 = bb_[1 * H + u]; a2 = bb_[2 * H + u]; a3 = bb_[3 * H + u];
#pragma unroll 4
    for (int k = 0; k < E; k++) {
        float xv = xr[k]; float4 w = Pb[k * H + u];
        a0 += xv * w.x; a1 += xv * w.y; a2 += xv * w.z; a3 += xv * w.w;
    }
    g = Gb + (size_t)n * 4 * H;
    g[0 * H + u] = a0; g[1 * H + u] = a1; g[2 * H + u] = a2; g[3 * H + u] = a3;
}

// ---------------- encoder layer-1 gate preactivations (input = concat(h0f,h0b))
__global__ void enc1_gates(const float* __restrict__ h0f, const float* __restrict__ h0b,
                           const float4* __restrict__ Pf, const float* __restrict__ bf_,
                           const float4* __restrict__ Pb, const float* __restrict__ bb_,
                           float* __restrict__ Gf, float* __restrict__ Gb) {
    int n = blockIdx.x;      // s*B+b
    int u = threadIdx.x;     // 256
    __shared__ float xr[D];
    xr[u] = h0f[(size_t)n * H + u];
    xr[H + u] = h0b[(size_t)n * H + u];
    __syncthreads();
    float a0 = bf_[0 * H + u], a1 = bf_[1 * H + u], a2 = bf_[2 * H + u], a3 = bf_[3 * H + u];
#pragma unroll 4
    for (int k = 0; k < D; k++) {
        float xv = xr[k]; float4 w = Pf[k * H + u];
        a0 += xv * w.x; a1 += xv * w.y; a2 += xv * w.z; a3 += xv * w.w;
    }
    float* g = Gf + (size_t)n * 4 * H;
    g[0 * H + u] = a0; g[1 * H + u] = a1; g[2 * H + u] = a2; g[3 * H + u] = a3;
    a0 = bb_[0 * H + u]; a1 = bb_[1 * H + u]; a2 = bb_[2 * H + u]; a3 = bb_[3 * H + u];
#pragma unroll 4
    for (int k = 0; k < D; k++) {
        float xv = xr[k]; float4 w = Pb[k * H + u];
        a0 += xv * w.x; a1 += xv * w.y; a2 += xv * w.z; a3 += xv * w.w;
    }
    g = Gb + (size_t)n * 4 * H;
    g[0 * H + u] = a0; g[1 * H + u] = a1; g[2 * H + u] = a2; g[3 * H + u] = a3;
}

// ---------------- encoder scan, bf16 weights, k-split 2. grid 32 = b*2+dir, 512 threads.
__global__ void __launch_bounds__(512) enc_scan_bf(
        const float* __restrict__ Gf, const float* __restrict__ Gb,
        const ushort* __restrict__ Pf, const ushort* __restrict__ Pb,  // [k][u][4g] bf16
        float* __restrict__ hof, float* __restrict__ hob,
        float* __restrict__ hfin /* [B][2H] */) {
    int blk = blockIdx.x;
    int dirb = blk & 1, b = blk >> 1;
    const float* G = dirb ? Gb : Gf;
    const uint2* P = (const uint2*)(dirb ? Pb : Pf);
    float* ho = dirb ? hob : hof;
    int tid = threadIdx.x;
    int u = tid & 255, kh = tid >> 8;
    __shared__ float hs[H];
    __shared__ float gsc[2][H][4];
    float c = 0.f, h = 0.f;
    if (tid < H) hs[tid] = 0.f;
    __syncthreads();
    for (int step = 0; step < S; step++) {
        int s = dirb ? (S - 1 - step) : step;
        float a0 = 0.f, a1 = 0.f, a2 = 0.f, a3 = 0.f;
        const uint2* wp = P + ((size_t)(kh * 128) * H + u);
#pragma unroll 4
        for (int i = 0; i < 128; i++) {
            float hv = hs[kh * 128 + i];
            uint2 w = wp[(size_t)i * H];
            a0 += hv * bflo(w.x); a1 += hv * bfhi(w.x);
            a2 += hv * bflo(w.y); a3 += hv * bfhi(w.y);
        }
        gsc[kh][u][0] = a0; gsc[kh][u][1] = a1; gsc[kh][u][2] = a2; gsc[kh][u][3] = a3;
        __syncthreads();
        if (tid < H) {
            const float* g = G + ((size_t)(s * B + b)) * (4 * H);
            float g0 = g[0 * H + u] + gsc[0][u][0] + gsc[1][u][0];
            float g1 = g[1 * H + u] + gsc[0][u][1] + gsc[1][u][1];
            float g2 = g[2 * H + u] + gsc[0][u][2] + gsc[1][u][2];
            float g3 = g[3 * H + u] + gsc[0][u][3] + gsc[1][u][3];
            float ig = sigm(g0), fg = sigm(g1), gg = tanhf(g2), og = sigm(g3);
            c = fg * c + ig * gg;
            h = og * tanhf(c);
            hs[u] = h;
            ho[((size_t)(s * B + b)) * H + u] = h;
        }
        __syncthreads();
    }
    if (tid < H) hfin[b * (2 * H) + dirb * H + u] = h;
}

// ---------------- decoder layer-0 input gates (teacher tokens). grid T*B (n=t*B+b), 512 thr.
__global__ void dec0_gates(const int* __restrict__ tgt, const float* __restrict__ emb,
                           const float4* __restrict__ P, const float* __restrict__ bias,
                           float* __restrict__ G) {
    int n = blockIdx.x;
    int t = n / B, b = n - t * B;
    int u = threadIdx.x;
    __shared__ float xr[E];
    int tok;
    if (t == 0) tok = START_ID;
    else { tok = tgt[b * T + (t - 1)]; if (tok >= V) tok = UNK_ID; }
    if (u < E) xr[u] = emb[(size_t)tok * E + u];
    __syncthreads();
    float a0 = bias[0 * D + u], a1 = bias[1 * D + u], a2 = bias[2 * D + u], a3 = bias[3 * D + u];
#pragma unroll 4
    for (int k = 0; k < E; k++) {
        float xv = xr[k]; float4 w = P[k * D + u];
        a0 += xv * w.x; a1 += xv * w.y; a2 += xv * w.z; a3 += xv * w.w;
    }
    float* g = G + (size_t)n * 4 * D;
    g[0 * D + u] = a0; g[1 * D + u] = a1; g[2 * D + u] = a2; g[3 * D + u] = a3;
}

// ---------------- grid barrier: monotone arrival counter (no reset -> race-free)
__device__ __forceinline__ void gridbar(int* cnt, int target) {
    __syncthreads();
    if (threadIdx.x == 0) {
        __threadfence();                       // release: my h-writes visible device-wide
        atomicAdd(cnt, 1);
        while (atomicAdd(cnt, 0) < target) __builtin_amdgcn_s_sleep(2);
        __threadfence();                       // acquire: invalidate stale cached h
    }
    __syncthreads();
}

// ---------------- decoder persistent 2-layer scan.
// grid 128 blocks (u-slice 4), 512 threads = (u_loc 4, g 4, kq 2, b 16).
// LDS-resident bf16 weight slices; h exchanged via global [b][512] f32 ping-pong buffers.
__global__ void __launch_bounds__(512) dec_scan2(
        const float* __restrict__ G0, const ushort* __restrict__ pb0,
        const ushort* __restrict__ pb1i, const ushort* __restrict__ pb1h,
        const float* __restrict__ b1, const float* __restrict__ hinit,
        float* __restrict__ h0g /* [2][B][D] */, float* __restrict__ h1g /* [2][B][D] */,
        float* __restrict__ h1out, int* __restrict__ bar) {
    __shared__ ushort W0s[4 * 4 * 512];    // [u_loc][g][k] 16 KB
    __shared__ ushort W1is[4 * 4 * 512];
    __shared__ ushort W1hs[4 * 4 * 512];
    __shared__ float red[4][4][2][16];
    int tid = threadIdx.x;
    int u0 = blockIdx.x * 4;
    int u_loc = tid >> 7, g = (tid >> 5) & 3, kq = (tid >> 4) & 1, b = tid & 15;

    // stage weight slices (each 16 KB, contiguous at u0*2048 ushorts)
    {
        const uint4* s0 = (const uint4*)(pb0 + (size_t)u0 * 2048);
        const uint4* s1 = (const uint4*)(pb1i + (size_t)u0 * 2048);
        const uint4* s2 = (const uint4*)(pb1h + (size_t)u0 * 2048);
        uint4* d0 = (uint4*)W0s; uint4* d1 = (uint4*)W1is; uint4* d2 = (uint4*)W1hs;
        for (int i = tid; i < 1024; i += 512) { d0[i] = s0[i]; d1[i] = s1[i]; d2[i] = s2[i]; }
    }
    float c0v = 0.f, c1v = 0.f;
    // init h ping-pong buffer 0 from hinit (same [b][512] layout)
    if (tid < 64) {
        int ul = tid >> 4, bb = tid & 15;
        h0g[bb * 512 + u0 + ul] = hinit[bb * 512 + u0 + ul];
        h1g[bb * 512 + u0 + ul] = hinit[B * D + bb * 512 + u0 + ul];
    }
    int arrivals = 0;
    gridbar(bar, (arrivals += NBLK_DEC));

    int cur = 0;
    for (int t = 0; t < T; t++) {
        float* h0c = h0g + cur * (B * D);
        float* h0n = h0g + (cur ^ 1) * (B * D);
        float* h1c = h1g + cur * (B * D);
        float* h1n = h1g + (cur ^ 1) * (B * D);
        // ---- phase A: layer-0 gate partial (one gate per thread, k-split 2)
        {
            const uint2* w = (const uint2*)(W0s + (u_loc * 4 + g) * 512) + kq * 64;
            const float* hp = h0c + b * 512 + kq * 256;
            float acc = 0.f;
#pragma unroll 4
            for (int i = 0; i < 64; i++) {
                uint2 wv = w[i];
                float4 hv = *(const float4*)(hp + i * 4);
                acc += bflo(wv.x) * hv.x + bfhi(wv.x) * hv.y + bflo(wv.y) * hv.z + bfhi(wv.y) * hv.w;
            }
            red[u_loc][g][kq][b] = acc;
        }
        __syncthreads();
        if (tid < 64) {
            int ul = tid >> 4, bb = tid & 15;
            const float* gg = G0 + ((size_t)(t * B + bb)) * 2048 + (u0 + ul);
            float g0 = gg[0]    + red[ul][0][0][bb] + red[ul][0][1][bb];
            float g1 = gg[512]  + red[ul][1][0][bb] + red[ul][1][1][bb];
            float g2 = gg[1024] + red[ul][2][0][bb] + red[ul][2][1][bb];
            float g3 = gg[1536] + red[ul][3][0][bb] + red[ul][3][1][bb];
            float ig = sigm(g0), fg = sigm(g1), gt = tanhf(g2), og = sigm(g3);
            c0v = fg * c0v + ig * gt;
            h0n[bb * 512 + u0 + ul] = og * tanhf(c0v);
        }
        gridbar(bar, (arrivals += NBLK_DEC));
        // ---- phase B: layer-1 gates = b1 + W1i*h0[t] + W1h*h1[t-1]
        {
            const uint2* wA = (const uint2*)(W1is + (u_loc * 4 + g) * 512) + kq * 64;
            const uint2* wB = (const uint2*)(W1hs + (u_loc * 4 + g) * 512) + kq * 64;
            const float* hA = h0n + b * 512 + kq * 256;
            const float* hB = h1c + b * 512 + kq * 256;
            float acc = 0.f;
#pragma unroll 4
            for (int i = 0; i < 64; i++) {
                uint2 wv = wA[i];
                float4 hv = *(const float4*)(hA + i * 4);
                acc += bflo(wv.x) * hv.x + bfhi(wv.x) * hv.y + bflo(wv.y) * hv.z + bfhi(wv.y) * hv.w;
                uint2 wv2 = wB[i];
                float4 hv2 = *(const float4*)(hB + i * 4);
                acc += bflo(wv2.x) * hv2.x + bfhi(wv2.x) * hv2.y + bflo(wv2.y) * hv2.z + bfhi(wv2.y) * hv2.w;
            }
            red[u_loc][g][kq][b] = acc;
        }
        __syncthreads();
        if (tid < 64) {
            int ul = tid >> 4, bb = tid & 15;
            int uu = u0 + ul;
            float g0 = b1[uu]        + red[ul][0][0][bb] + red[ul][0][1][bb];
            float g1 = b1[512 + uu]  + red[ul][1][0][bb] + red[ul][1][1][bb];
            float g2 = b1[1024 + uu] + red[ul][2][0][bb] + red[ul][2][1][bb];
            float g3 = b1[1536 + uu] + red[ul][3][0][bb] + red[ul][3][1][bb];
            float ig = sigm(g0), fg = sigm(g1), gt = tanhf(g2), og = sigm(g3);
            c1v = fg * c1v + ig * gt;
            float h1n_v = og * tanhf(c1v);
            h1n[bb * 512 + uu] = h1n_v;
            h1out[((size_t)(t * B + bb)) * 512 + uu] = h1n_v;
        }
        gridbar(bar, (arrivals += NBLK_DEC));
        cur ^= 1;
    }
}

// ---------------- transpose enc hidden to [b][k(512)][s] for coalesced score dots
__global__ void build_encht(const float* __restrict__ h1f, const float* __restrict__ h1b,
                            float* __restrict__ et) {
    int blk = blockIdx.x;                 // b*256 + kt*16 + st
    int b = blk >> 8, rem = blk & 255;
    int kt = rem >> 4, st = rem & 15;
    int c = threadIdx.x & 31, r = threadIdx.x >> 5;   // r in 0..7
    __shared__ float tile[32][33];
#pragma unroll
    for (int i = 0; i < 4; i++) {
        int sl = r + i * 8;               // s_local
        int s = st * 32 + sl;
        int k = kt * 32 + c;              // lane-contiguous over k
        float v = (k < H) ? h1f[((size_t)(s * B + b)) * H + k]
                          : h1b[((size_t)(s * B + b)) * H + (k - H)];
        tile[c][sl] = v;                  // tile[k_local][s_local]
    }
    __syncthreads();
#pragma unroll
    for (int i = 0; i < 4; i++) {
        int kl = r + i * 8;
        et[(size_t)b * D * S + (size_t)(kt * 32 + kl) * S + st * 32 + c] = tile[kl][c];
    }
}

// ---------------- q projections. grid T*B (n=t*B+b), 512 threads
__global__ void qproj(const float* __restrict__ h1d, const float* __restrict__ Wenc,
                      const float* __restrict__ Wdec, float* __restrict__ qe, float* __restrict__ qd) {
    int n = blockIdx.x;
    int o = threadIdx.x;
    __shared__ float hr[D];
    hr[o] = h1d[(size_t)n * D + o];
    __syncthreads();
    float ae = 0.f, ad = 0.f;
#pragma unroll 4
    for (int k = 0; k < D; k++) {
        float hk = hr[k];
        ae += hk * Wenc[k * D + o];
        ad += hk * Wdec[k * D + o];
    }
    qe[(size_t)n * D + o] = ae;
    qd[(size_t)n * D + o] = ad;
}

// ---------------- e = exp(min(score,30)). grid B*T (bt=b*T+t), 512 threads (s)
__global__ void escore(const float* __restrict__ qe, const float* __restrict__ et,
                       float* __restrict__ ew) {
    int bt = blockIdx.x;
    int b = bt / T, t = bt - b * T;
    int sx = threadIdx.x;
    __shared__ float q[D];
    q[sx] = qe[((size_t)(t * B + b)) * D + sx];
    __syncthreads();
    float acc = 0.f;
    const float* eb = et + (size_t)b * D * S + sx;
#pragma unroll 4
    for (int k = 0; k < D; k++) { acc += q[k] * eb[0]; eb += S; }
    acc = fminf(acc, 30.0f);
    ew[(size_t)bt * S + sx] = __expf(acc);
}

// ---------------- temporal normalization (prefix over t, in place)
__global__ void temporal_k(float* __restrict__ ew) {
    int i = blockIdx.x * blockDim.x + threadIdx.x;
    if (i >= B * S) return;
    int b = i / S, sx = i - b * S;
    float cum = 0.f;
    for (int t = 0; t < T; t++) {
        size_t idx = ((size_t)(b * T + t)) * S + sx;
        float v = ew[idx];
        ew[idx] = v / (t == 0 ? 1.0f : (cum + 1e-8f));
        cum += v;
    }
}

// ---------------- attention softmax over s + enc context + copy prob. grid B*T, 512 thr
__global__ void attnctx(const float* __restrict__ ew, const int* __restrict__ ids,
                        const int* __restrict__ tgt,
                        const float* __restrict__ h1f, const float* __restrict__ h1b,
                        float* __restrict__ ectx, float* __restrict__ copyp) {
    int bt = blockIdx.x;
    int b = bt / T, t = bt - b * T;
    int tid = threadIdx.x;
    __shared__ float aw[S];
    __shared__ float red[512];
    float v = ew[(size_t)bt * S + tid];
    int tok = ids[b * S + tid];
    bool pad = (tok == PAD_ID);
    float vm = pad ? -INFINITY : v;
    red[tid] = vm; __syncthreads();
    for (int w = 256; w > 0; w >>= 1) { if (tid < w) red[tid] = fmaxf(red[tid], red[tid + w]); __syncthreads(); }
    float m = red[0]; __syncthreads();
    float ex = pad ? 0.f : __expf(vm - m);
    red[tid] = ex; __syncthreads();
    for (int w = 256; w > 0; w >>= 1) { if (tid < w) red[tid] += red[tid + w]; __syncthreads(); }
    float Z = red[0]; __syncthreads();
    float a = ex / Z;
    aw[tid] = a;
    int nt = tgt[b * T + t];
    red[tid] = (tok == nt) ? a : 0.f; __syncthreads();
    for (int w = 256; w > 0; w >>= 1) { if (tid < w) red[tid] += red[tid + w]; __syncthreads(); }
    if (tid == 0) copyp[bt] = red[0];
    __syncthreads();
    int d = tid;
    const float* hp = (d < H) ? (h1f + (size_t)b * H + d) : (h1b + (size_t)b * H + (d - H));
    float acc = 0.f;
#pragma unroll 4
    for (int s2 = 0; s2 < S; s2++) { acc += aw[s2] * hp[0]; hp += B * H; }
    ectx[(size_t)bt * D + d] = acc;
}

// ---------------- intra-decoder attention. grid B*T, 128 threads
__global__ void decattn(const float* __restrict__ qd, const float* __restrict__ h1d,
                        float* __restrict__ dctx) {
    int bt = blockIdx.x;
    int b = bt / T, t = bt - b * T;
    int tid = threadIdx.x;
    __shared__ float q[D];
    __shared__ float wl[T];
    __shared__ float red[128];
    for (int i = tid; i < D; i += 128) q[i] = qd[((size_t)(t * B + b)) * D + i];
    __syncthreads();
    float sc = -INFINITY;
    if (tid < t) {
        const float* hu = h1d + ((size_t)(tid * B + b)) * D;
        float a = 0.f;
#pragma unroll 4
        for (int k = 0; k < D; k++) a += q[k] * hu[k];
        sc = a;
    }
    red[tid] = sc; __syncthreads();
    for (int w = 64; w > 0; w >>= 1) { if (tid < w) red[tid] = fmaxf(red[tid], red[tid + w]); __syncthreads(); }
    float m = red[0]; __syncthreads();
    float ex = (tid < t) ? __expf(sc - m) : 0.f;
    red[tid] = ex; __syncthreads();
    for (int w = 64; w > 0; w >>= 1) { if (tid < w) red[tid] += red[tid + w]; __syncthreads(); }
    float Z = red[0]; __syncthreads();
    wl[tid] = (t > 0) ? (ex / Z) : 0.f;
    __syncthreads();
    for (int d = tid; d < D; d += 128) {
        float acc = 0.f;
        for (int u = 0; u < t; u++) acc += wl[u] * h1d[((size_t)(u * B + b)) * D + d];
        dctx[(size_t)bt * D + d] = acc;
    }
}

// ---------------- concat + p_gen. grid B*T, 512 threads
__global__ void concat_k(const float* __restrict__ h1d, const float* __restrict__ ectx,
                         const float* __restrict__ dctx, const float* __restrict__ sW,
                         const float* __restrict__ sb, float* __restrict__ cc,
                         float* __restrict__ pgen) {
    int bt = blockIdx.x;
    int b = bt / T, t = bt - b * T;
    int d = threadIdx.x;
    __shared__ float red[512];
    float v0 = h1d[((size_t)(t * B + b)) * D + d];
    float v1 = ectx[(size_t)bt * D + d];
    float v2 = dctx[(size_t)bt * D + d];
    float* c = cc + (size_t)bt * C3;
    c[d] = v0; c[D + d] = v1; c[2 * D + d] = v2;
    red[d] = v0 * sW[d] + v1 * sW[D + d] + v2 * sW[2 * D + d];
    __syncthreads();
    for (int w = 256; w > 0; w >>= 1) { if (d < w) red[d] += red[d + w]; __syncthreads(); }
    if (d == 0) pgen[bt] = 1.f / (1.f + __expf(-(red[0] + sb[0])));
}

// ---------------- out_proj, packed-k layout for MFMA B-fragments.
__global__ void outprojT_k(const float* __restrict__ emb, const float* __restrict__ Wvoc,
                           __hip_bfloat16* __restrict__ outT2) {
    int j0 = blockIdx.x * 32;
    int jl = threadIdx.x & 31, oq = threadIdx.x >> 5;   // oq in 0..7
    __shared__ float er[32][E + 1];                      // +1 pad
    for (int i = threadIdx.x; i < 32 * E; i += 256) {
        int jj = i >> 7, e = i & 127;
        int j = j0 + jj;
        er[jj][e] = (j < VO) ? emb[(size_t)(3 + j) * E + e] : 0.f;
    }
    __syncthreads();
    int j = j0 + jl;
#pragma unroll 1
    for (int i = 0; i < 24; i++) {
        int o = oq * 24 + i;                             // octet index 0..191
        int k0 = o * 8;
        float acc[8];
#pragma unroll
        for (int kk = 0; kk < 8; kk++) acc[kk] = 0.f;
#pragma unroll 4
        for (int e = 0; e < E; e++) {
            float x = er[jl][e];
            float4 w0 = *(const float4*)(Wvoc + (size_t)e * C3 + k0);
            float4 w1 = *(const float4*)(Wvoc + (size_t)e * C3 + k0 + 4);
            acc[0] += x * w0.x; acc[1] += x * w0.y; acc[2] += x * w0.z; acc[3] += x * w0.w;
            acc[4] += x * w1.x; acc[5] += x * w1.y; acc[6] += x * w1.z; acc[7] += x * w1.w;
        }
        short8 v;
#pragma unroll
        for (int kk = 0; kk < 8; kk++) v[kk] = bf16s(tanhf(acc[kk]));
        *reinterpret_cast<short8*>((char*)outT2 + ((size_t)o * JS + j) * 16) = v;
    }
}

// ---------------- vocab GEMM via MFMA + fused online softmax partials.
__global__ void __launch_bounds__(512) vocab_mfma(
        const __hip_bfloat16* __restrict__ outT2, const float* __restrict__ cc,
        const float* __restrict__ ob, const int* __restrict__ tgt,
        float* __restrict__ pbuf) {
    __shared__ __align__(16) short As[32 * 1536];        // bf16 A tile, chunk-XOR swizzled
    __shared__ float wm[8][32], ws_[8][32], wg[8][32];
    __shared__ int jstar_s[32];
    int bid = blockIdx.x;
    int rb = bid & 63, q = bid >> 6;
    int row0 = rb * 32;
    int tid = threadIdx.x;

    {
        int r = tid >> 4, cpos = tid & 15;
        const float* src = cc + (size_t)(row0 + r) * C3;
        int r7 = r & 7;
        short* dst = As + r * C3;
#pragma unroll
        for (int ii = 0; ii < 12; ii++) {
            int c = ii * 16 + cpos;                      // chunk 0..191 (8 bf16 each)
            float4 f0 = *(const float4*)(src + c * 8);
            float4 f1 = *(const float4*)(src + c * 8 + 4);
            short8 v;
            v[0] = bf16s(f0.x); v[1] = bf16s(f0.y); v[2] = bf16s(f0.z); v[3] = bf16s(f0.w);
            v[4] = bf16s(f1.x); v[5] = bf16s(f1.y); v[6] = bf16s(f1.z); v[7] = bf16s(f1.w);
            *reinterpret_cast<short8*>(dst + ((c ^ r7) << 3)) = v;
        }
    }
    if (tid < 32) {
        int nt = tgt[row0 + tid];
        int ix = nt - 3;
        ix = ix < 0 ? 0 : (ix > VO - 1 ? VO - 1 : ix);
        jstar_s[tid] = ix;
    }
    __syncthreads();

    int lane = tid & 63, wid = tid >> 6;
    int wr = wid >> 2, wc = wid & 3;
    int cl = lane & 15, g = lane >> 4;
    int rowA = wr * 16 + cl;
    const short* Abase = As + rowA * C3;
    int r7 = rowA & 7;
    int jst[4];
    float m[4], sacc[4], gl[4];
#pragma unroll
    for (int i = 0; i < 4; i++) {
        jst[i] = jstar_s[wr * 16 + g * 4 + i];
        m[i] = -1e30f; sacc[i] = 0.f; gl[i] = -1e30f;
    }

    int jb0 = q * 8192;
    int jqend = (jb0 + 8192 < VO) ? jb0 + 8192 : VO;
    int nmt = (jqend - jb0 + 127) >> 7;
    for (int ti = 0; ti < nmt; ti++) {
        int jA = jb0 + ti * 128 + wc * 32 + cl;
        const char* pB = (const char*)outT2 + ((size_t)g * JS + jA) * 16;
        f32x4 acc0 = {0.f, 0.f, 0.f, 0.f}, acc1 = {0.f, 0.f, 0.f, 0.f};
#pragma unroll
        for (int s = 0; s < 48; s++) {
            short8 a = *reinterpret_cast<const short8*>(Abase + (((s * 4 + g) ^ r7) << 3));
            short8 b0 = *reinterpret_cast<const short8*>(pB + (size_t)s * (4 * JS * 16));
            short8 b1 = *reinterpret_cast<const short8*>(pB + (size_t)s * (4 * JS * 16) + 256);
            acc0 = __builtin_amdgcn_mfma_f32_16x16x32_bf16(a, b0, acc0, 0, 0, 0);
            acc1 = __builtin_amdgcn_mfma_f32_16x16x32_bf16(a, b1, acc1, 0, 0, 0);
        }
#pragma unroll
        for (int X = 0; X < 2; X++) {
            int j = jA + X * 16;
            if (j < jqend) {
                float obj = ob[j];
#pragma unroll
                for (int i = 0; i < 4; i++) {
                    float L = (X ? acc1[i] : acc0[i]) + obj;
                    if (j == jst[i]) gl[i] = L;
                    float mn = fmaxf(m[i], L);
                    sacc[i] = sacc[i] * __expf(m[i] - mn) + __expf(L - mn);
                    m[i] = mn;
                }
            }
        }
    }

#pragma unroll
    for (int i = 0; i < 4; i++) {
        for (int mask = 1; mask < 16; mask <<= 1) {
            float om = __shfl_xor(m[i], mask);
            float os = __shfl_xor(sacc[i], mask);
            float mn = fmaxf(m[i], om);
            sacc[i] = sacc[i] * __expf(m[i] - mn) + os * __expf(om - mn);
            m[i] = mn;
            gl[i] = fmaxf(gl[i], __shfl_xor(gl[i], mask));
        }
    }
    if (cl == 0) {
#pragma unroll
        for (int i = 0; i < 4; i++) {
            int rl = wr * 16 + g * 4 + i;
            wm[wid][rl] = m[i]; ws_[wid][rl] = sacc[i]; wg[wid][rl] = gl[i];
        }
    }
    __syncthreads();
    if (tid < 32) {
        float M = -1e30f, SS = 0.f, GL = -1e30f;
        int w0 = (tid >> 4) * 4;
#pragma unroll
        for (int w = 0; w < 4; w++) {
            float mq = wm[w0 + w][tid], sq = ws_[w0 + w][tid], gq = wg[w0 + w][tid];
            float mn = fmaxf(M, mq);
            SS = SS * __expf(M - mn) + sq * __expf(mq - mn);
            M = mn;
            GL = fmaxf(GL, gq);
        }
        float* o = pbuf + ((size_t)bid * 32 + tid) * 4;
        o[0] = M; o[1] = SS; o[2] = GL;
    }
}

// ---------------- combine quarter-partials + pointer mix + NLL. grid B, 128 threads.
__global__ void combine_nll_k(const float* __restrict__ pbuf, const int* __restrict__ tgt,
                              const float* __restrict__ pgen, const float* __restrict__ copyp,
                              const int* __restrict__ tlen, float* __restrict__ out) {
    int b = blockIdx.x, t = threadIdx.x;
    int row = b * T + t;
    int rb = row >> 5, r = row & 31;
    float M = -1e30f, SS = 0.f, GL = -1e30f;
#pragma unroll
    for (int q = 0; q < 4; q++) {
        const float* p = pbuf + ((size_t)(q * 64 + rb) * 32 + r) * 4;
        float mq = p[0], sq = p[1], gq = p[2];
        float mn = fmaxf(M, mq);
        SS = SS * __expf(M - mn) + sq * __expf(mq - mn);
        M = mn;
        GL = fmaxf(GL, gq);
    }
    int nt = tgt[row];
    float genp = (nt >= 3 && nt < V) ? __expf(GL - M) / SS : 0.f;
    float pg = pgen[row];
    float p = pg * genp + (1.f - pg) * copyp[row];
    __shared__ float red[128];
    red[t] = (t < tlen[b]) ? -logf(p + 1e-9f) : 0.f;
    __syncthreads();
    for (int w = 64; w > 0; w >>= 1) { if (t < w) red[t] += red[t + w]; __syncthreads(); }
    if (t == 0) out[b] = red[0];
}

extern "C" void kernel_launch(void* const* d_in, const int* in_sizes, int n_in,
                              void* d_out, int out_size, void* d_ws, size_t ws_size,
                              hipStream_t stream) {
    const int* input_ids = (const int*)d_in[0];
    const int* target_ids = (const int*)d_in[1];
    const int* tlen = (const int*)d_in[3];
    const float* emb = (const float*)d_in[5];
    const float* eWih0f = (const float*)d_in[6],  *eWhh0f = (const float*)d_in[7],  *eb0f = (const float*)d_in[8];
    const float* eWih0b = (const float*)d_in[9],  *eWhh0b = (const float*)d_in[10], *eb0b = (const float*)d_in[11];
    const float* eWih1f = (const float*)d_in[12], *eWhh1f = (const float*)d_in[13], *eb1f = (const float*)d_in[14];
    const float* eWih1b = (const float*)d_in[15], *eWhh1b = (const float*)d_in[16], *eb1b = (const float*)d_in[17];
    const float* dWih0 = (const float*)d_in[18], *dWhh0 = (const float*)d_in[19], *db0 = (const float*)d_in[20];
    const float* dWih1 = (const float*)d_in[21], *dWhh1 = (const float*)d_in[22], *db1 = (const float*)d_in[23];
    const float* Wenc = (const float*)d_in[24], *Wdec = (const float*)d_in[25];
    const float* Wvoc = (const float*)d_in[26], *sW = (const float*)d_in[27], *sb = (const float*)d_in[28];
    const float* ob = (const float*)d_in[29];
    float* out = (float*)d_out;
    (void)ws_size; (void)n_in; (void)in_sizes; (void)out_size;

    // ============ workspace layout (~145 MB, phase-aliased) ============
    // Region A (98,304,000 B):
    //   phase 1: f32 gate-packed Wih + bf16 scan weights [0 .. 14,680,064)
    //            G0f @23,068,672 (33.5M), G0b @56,623,104 (33.5M)
    //   phase 2: Gd0 @23,068,672 (16.8M), ench @39,845,888, ectx/dctx @56M..
    //   phase 3: outT2 bf16 [0 .. 98,304,000)
    char* A = (char*)d_ws;
    float4* pWih0f = (float4*)(A + 0);              //  512 KB f32 gate-packed
    float4* pWih0b = (float4*)(A + 524288);
    float4* pWih1f = (float4*)(A + 1048576);        //  2 MB
    float4* pWih1b = (float4*)(A + 3145728);
    float4* pdWih0 = (float4*)(A + 5242880);        //  1 MB
    ushort* peW0f  = (ushort*)(A + 6291456);        //  512 KB bf16 [k][u][g]
    ushort* peW0b  = (ushort*)(A + 6815744);
    ushort* peW1f  = (ushort*)(A + 7340032);
    ushort* peW1b  = (ushort*)(A + 7864320);
    ushort* pb0    = (ushort*)(A + 8388608);        //  2 MB bf16 [u][g][k]
    ushort* pb1i   = (ushort*)(A + 10485760);
    ushort* pb1h   = (ushort*)(A + 12582912);       //  ends 14,680,064
    float* G0f = (float*)(A + 23068672);
    float* G0b = (float*)(A + 56623104);
    float* Gd0 = (float*)(A + 23068672);            // aliases G0f (dead after enc scans)
    float* ench = (float*)(A + 39845888);
    float* ectx = (float*)(A + 56623104);
    float* dctx = (float*)(A + 60817408);
    __hip_bfloat16* outT2 = (__hip_bfloat16*)A;     // whole region, after concat_k

    char* Bh = A + 98304000;
    float* h0f = (float*)(Bh + 0);
    float* h0b = (float*)(Bh + 8388608);
    float* h1d = (float*)(Bh + 0);                  // aliases h0f (dead after enc1_gates)
    float* qe  = (float*)(Bh + 4194304);
    float* qd  = (float*)(Bh + 8388608);
    float* ew  = (float*)(Bh + 12582912);
    char* Cr = Bh + 16777216;
    float* h1f = (float*)(Cr + 0);                  // 8,388,608
    float* h1b = (float*)(Cr + 8388608);            // 8,388,608
    float* cc  = (float*)(Cr + 16777216);           // 12,582,912
    float* dec_init = (float*)(Cr + 29360128);      // 65,536
    float* pgen  = (float*)(Cr + 29425664);         // 8,192
    float* copyp = (float*)(Cr + 29433856);         // 8,192
    float* pbuf  = (float*)(Cr + 29442048);         // 131,072
    float* h0g   = (float*)(Cr + 29573120);         // 65,536 (2×[B][D])
    float* h1g   = (float*)(Cr + 29638656);         // 65,536
    int*   bar   = (int*)(Cr + 29704192);           // 256
    // total ≈ 144.8 MB

    hipMemsetAsync(bar, 0, 256, stream);

    auto pack = [&](const float* W, float4* P, int Hn, int K) {
        int total = Hn * K;
        hipLaunchKernelGGL(pack4_kernel, dim3((total + 255) / 256), dim3(256), 0, stream, W, P, Hn, K);
    };
    pack(eWih0f, pWih0f, H, E);
    pack(eWih0b, pWih0b, H, E);
    pack(eWih1f, pWih1f, H, D);
    pack(eWih1b, pWih1b, H, D);
    pack(dWih0, pdWih0, D, E);
    hipLaunchKernelGGL(packenc_k, dim3(H * H * 4 / 256), dim3(256), 0, stream, eWhh0f, peW0f);
    hipLaunchKernelGGL(packenc_k, dim3(H * H * 4 / 256), dim3(256), 0, stream, eWhh0b, peW0b);
    hipLaunchKernelGGL(packenc_k, dim3(H * H * 4 / 256), dim3(256), 0, stream, eWhh1f, peW1f);
    hipLaunchKernelGGL(packenc_k, dim3(H * H * 4 / 256), dim3(256), 0, stream, eWhh1b, peW1b);
    hipLaunchKernelGGL(packdec_k, dim3(D * D * 4 / 256), dim3(256), 0, stream, dWhh0, pb0);
    hipLaunchKernelGGL(packdec_k, dim3(D * D * 4 / 256), dim3(256), 0, stream, dWih1, pb1i);
    hipLaunchKernelGGL(packdec_k, dim3(D * D * 4 / 256), dim3(256), 0, stream, dWhh1, pb1h);

    hipLaunchKernelGGL(enc0_gates, dim3(S * B), dim3(H), 0, stream,
                       input_ids, emb, pWih0f, eb0f, pWih0b, eb0b, G0f, G0b);
    hipLaunchKernelGGL(enc_scan_bf, dim3(32), dim3(512), 0, stream,
                       G0f, G0b, peW0f, peW0b, h0f, h0b, dec_init);
    hipLaunchKernelGGL(enc1_gates, dim3(S * B), dim3(H), 0, stream,
                       h0f, h0b, pWih1f, eb1f, pWih1b, eb1b, G0f, G0b);
    hipLaunchKernelGGL(enc_scan_bf, dim3(32), dim3(512), 0, stream,
                       G0f, G0b, peW1f, peW1b, h1f, h1b, dec_init + B * D);
    hipLaunchKernelGGL(dec0_gates, dim3(T * B), dim3(D), 0, stream,
                       target_ids, emb, pdWih0, db0, Gd0);
    hipLaunchKernelGGL(dec_scan2, dim3(NBLK_DEC), dim3(512), 0, stream,
                       Gd0, pb0, pb1i, pb1h, db1, dec_init, h0g, h1g, h1d, bar);
    hipLaunchKernelGGL(build_encht, dim3(B * 256), dim3(256), 0, stream, h1f, h1b, ench);
    hipLaunchKernelGGL(qproj, dim3(T * B), dim3(D), 0, stream, h1d, Wenc, Wdec, qe, qd);
    hipLaunchKernelGGL(escore, dim3(B * T), dim3(S), 0, stream, qe, ench, ew);
    hipLaunchKernelGGL(temporal_k, dim3((B * S + 255) / 256), dim3(256), 0, stream, ew);
    hipLaunchKernelGGL(attnctx, dim3(B * T), dim3(S), 0, stream,
                       ew, input_ids, target_ids, h1f, h1b, ectx, copyp);
    hipLaunchKernelGGL(decattn, dim3(B * T), dim3(T), 0, stream, qd, h1d, dctx);
    hipLaunchKernelGGL(concat_k, dim3(B * T), dim3(D), 0, stream,
                       h1d, ectx, dctx, sW, sb, cc, pgen);
    hipLaunchKernelGGL(outprojT_k, dim3(1000), dim3(256), 0, stream, emb, Wvoc, outT2);
    hipLaunchKernelGGL(vocab_mfma, dim3(256), dim3(512), 0, stream,
                       outT2, cc, ob, target_ids, pbuf);
    hipLaunchKernelGGL(combine_nll_k, dim3(B), dim3(T), 0, stream,
                       pbuf, target_ids, pgen, copyp, tlen, out);
}